// Round 10
// baseline (288.291 us; speedup 1.0000x reference)
//
#include <hip/hip_runtime.h>
#include <stdint.h>

// Problem constants (match reference)
#define kN   20000
#define kE   160000
#define kET  (kN + kE)   // edges incl self loops = 180000
#define kF   256
#define kHID 64
#define kH   4
#define kHC  16
#define kC   10
#define kK   3
#define kCST 1e-5f
#define kBN  32          // nodes per proj block (625 blocks)
#define kNB  ((kN + 255) / 256)   // 79 partial-scan blocks
#define kMS  ((size_t)kN * 48)    // slice stride in words (48 words = 40 M + 8 Kt)

__device__ __forceinline__ uint16_t f2bf(float x) {
    uint32_t u = __float_as_uint(x);
    u += 0x7fffu + ((u >> 16) & 1u);   // round-to-nearest-even
    return (uint16_t)(u >> 16);
}
__device__ __forceinline__ float lo16(uint32_t p) { return __uint_as_float(p << 16); }
__device__ __forceinline__ float hi16(uint32_t p) { return __uint_as_float(p & 0xffff0000u); }
__device__ __forceinline__ uint32_t pack2(float a, float b) {
    return ((uint32_t)f2bf(b) << 16) | (uint32_t)f2bf(a);
}

// ---- degree histogram over col (incl self loops) ----
__global__ void deg_kernel(const int* __restrict__ ei, int* __restrict__ deg) {
    int e = blockIdx.x * blockDim.x + threadIdx.x;
    if (e >= kET) return;
    int c = (e < kE) ? ei[kE + e] : (e - kE);
    atomicAdd(&deg[c], 1);
}

// ---- parallel scan stage 1: per-block (256) sums of deg ----
__global__ __launch_bounds__(256) void degsum_kernel(const int* __restrict__ deg,
                                                     int* __restrict__ partial) {
    __shared__ int sw[4];
    int t = threadIdx.x;
    int idx = blockIdx.x * 256 + t;
    int v = (idx < kN) ? deg[idx] : 0;
#pragma unroll
    for (int off = 32; off >= 1; off >>= 1) v += __shfl_xor(v, off, 64);
    if ((t & 63) == 0) sw[t >> 6] = v;
    __syncthreads();
    if (t == 0) partial[blockIdx.x] = sw[0] + sw[1] + sw[2] + sw[3];
}

// ---- stage 2: scan the 79 partials (exclusive) + gammas ----
__global__ __launch_bounds__(128) void midscan_kernel(
    const int* __restrict__ partial, int* __restrict__ offsets,
    const float* __restrict__ hopwise, const float* __restrict__ temp,
    float* __restrict__ gammas) {
    __shared__ int ws0;
    int t = threadIdx.x;
    int v = (t < kNB) ? partial[t] : 0;
    int incl = v;
#pragma unroll
    for (int off = 1; off < 64; off <<= 1) {
        int u = __shfl_up(incl, off, 64);
        if ((t & 63) >= off) incl += u;
    }
    if (t == 63) ws0 = incl;
    __syncthreads();
    int add = (t >= 64) ? ws0 : 0;
    if (t < kNB) offsets[t] = add + incl - v;
    if (t == 0) {
        for (int k = 1; k <= kK; ++k) {
            float mx = -1e30f;
            for (int h = 0; h < kH; ++h) mx = fmaxf(mx, temp[h * (kK + 1) + k]);
            float ex[kH]; float sum = 0.f;
            for (int h = 0; h < kH; ++h) { ex[h] = __expf(temp[h * (kK + 1) + k] - mx); sum += ex[h]; }
            for (int h = 0; h < kH; ++h) gammas[(k - 1) * kH + h] = hopwise[k] * ex[h] / sum;
        }
    }
}

// ---- stage 3: ptr[idx] = offsets[b] + in-block exclusive prefix ----
__global__ __launch_bounds__(256) void ptrw_kernel(const int* __restrict__ deg,
                                                   const int* __restrict__ offsets,
                                                   int* __restrict__ ptr) {
    __shared__ int sw[4];
    int t = threadIdx.x;
    int idx = blockIdx.x * 256 + t;
    int v = (idx < kN) ? deg[idx] : 0;
    int incl = v;
#pragma unroll
    for (int off = 1; off < 64; off <<= 1) {
        int u = __shfl_up(incl, off, 64);
        if ((t & 63) >= off) incl += u;
    }
    int wid = t >> 6;
    if ((t & 63) == 63) sw[wid] = incl;
    __syncthreads();
    int wadd = 0;
    for (int j = 0; j < 4; ++j) wadd += (j < wid) ? sw[j] : 0;
    int excl = offsets[blockIdx.x] + wadd + incl - v;
    if (idx < kN) ptr[idx] = excl;
    if (idx == kN - 1) ptr[kN] = excl + v;
}

// ---- CSR (by col) build: scatter (row, norm); norm from deg via rsqrt ----
__global__ void scatter_kernel(const int* __restrict__ ei, const int* __restrict__ deg,
                               const int* __restrict__ ptr, int* __restrict__ cursor,
                               int* __restrict__ src, float* __restrict__ wgt) {
    int e = blockIdx.x * blockDim.x + threadIdx.x;
    if (e >= kET) return;
    int r, c;
    if (e < kE) { r = ei[e]; c = ei[kE + e]; } else { r = c = e - kE; }
    float wv = rsqrtf((float)deg[r]) * rsqrtf((float)deg[c]);
    int pos = ptr[c] + atomicAdd(&cursor[c], 1);
    src[pos] = r;
    wgt[pos] = wv;
}

// ---- fused projections, 32 nodes/block x 625 blocks.
//      x = relu(feat@W_in+b); Q/K = 1+elu(x@Wq/Wk+b); V = x@Wv+b (f32 out);
//      hidden = V*hopwise[0]; Q,Kt f32 to global. NO M materialization.
__global__ __launch_bounds__(256) void proj_kernel(
    const float* __restrict__ feat, const float* __restrict__ W_in, const float* __restrict__ b_in,
    const float* __restrict__ Wq, const float* __restrict__ bq,
    const float* __restrict__ Wk, const float* __restrict__ bk,
    const float* __restrict__ Wv, const float* __restrict__ bv,
    const float* __restrict__ hopwise,
    float* __restrict__ Qg, float* __restrict__ Ktg, float* __restrict__ hidden,
    float* __restrict__ Vg) {
    __shared__ float sF[kBN * 68];   // feat k-tile
    __shared__ float sW[64 * 68];    // W_in tile -> Wq -> Wk -> Wv
    __shared__ float sX[kBN * 68];   // x

    int t = threadIdx.x;
    int tx = t & 15, ty = t >> 4;    // 16 x 16 thread grid
    int n0 = blockIdx.x * kBN;
    int r0 = ty * 2, r1 = ty * 2 + 1;

    float acc[2][4];
#pragma unroll
    for (int i = 0; i < 2; ++i)
#pragma unroll
        for (int j = 0; j < 4; ++j) acc[i][j] = 0.f;

    for (int ks = 0; ks < 4; ++ks) {
        int k0 = ks * 64;
#pragma unroll
        for (int i = 0; i < 2; ++i) {
            int slot = t + 256 * i;
            int row = slot >> 4, cg = slot & 15;
            *(float4*)&sF[row * 68 + cg * 4] =
                *(const float4*)&feat[(size_t)(n0 + row) * kF + k0 + cg * 4];
        }
#pragma unroll
        for (int i = 0; i < 4; ++i) {
            int slot = t + 256 * i;
            int row = slot >> 4, cg = slot & 15;
            *(float4*)&sW[row * 68 + cg * 4] =
                *(const float4*)&W_in[(size_t)(k0 + row) * kHID + cg * 4];
        }
        __syncthreads();
#pragma unroll 8
        for (int kk = 0; kk < 64; ++kk) {
            float4 b = *(float4*)&sW[kk * 68 + tx * 4];
            float a0 = sF[r0 * 68 + kk], a1 = sF[r1 * 68 + kk];
            acc[0][0] += a0 * b.x; acc[0][1] += a0 * b.y;
            acc[0][2] += a0 * b.z; acc[0][3] += a0 * b.w;
            acc[1][0] += a1 * b.x; acc[1][1] += a1 * b.y;
            acc[1][2] += a1 * b.z; acc[1][3] += a1 * b.w;
        }
        __syncthreads();
    }
    {
        float bb[4];
#pragma unroll
        for (int j = 0; j < 4; ++j) bb[j] = b_in[tx * 4 + j];
#pragma unroll
        for (int i = 0; i < 2; ++i) {
            float4 xr;
            xr.x = fmaxf(acc[i][0] + bb[0], 0.f);
            xr.y = fmaxf(acc[i][1] + bb[1], 0.f);
            xr.z = fmaxf(acc[i][2] + bb[2], 0.f);
            xr.w = fmaxf(acc[i][3] + bb[3], 0.f);
            *(float4*)&sX[(r0 + i) * 68 + tx * 4] = xr;
        }
    }
#pragma unroll
    for (int i = 0; i < 4; ++i) {
        int slot = t + 256 * i;
        int row = slot >> 4, cg = slot & 15;
        *(float4*)&sW[row * 68 + cg * 4] = *(const float4*)&Wq[(size_t)row * kHID + cg * 4];
    }
    __syncthreads();

    float qa[2][4];
#pragma unroll
    for (int i = 0; i < 2; ++i)
#pragma unroll
        for (int j = 0; j < 4; ++j) qa[i][j] = 0.f;
#pragma unroll 8
    for (int kk = 0; kk < 64; ++kk) {
        float4 b = *(float4*)&sW[kk * 68 + tx * 4];
        float a0 = sX[r0 * 68 + kk], a1 = sX[r1 * 68 + kk];
        qa[0][0] += a0 * b.x; qa[0][1] += a0 * b.y;
        qa[0][2] += a0 * b.z; qa[0][3] += a0 * b.w;
        qa[1][0] += a1 * b.x; qa[1][1] += a1 * b.y;
        qa[1][2] += a1 * b.z; qa[1][3] += a1 * b.w;
    }
    {
        float bqv[4];
#pragma unroll
        for (int j = 0; j < 4; ++j) bqv[j] = bq[tx * 4 + j];
#pragma unroll
        for (int i = 0; i < 2; ++i) {
            float4 qv;
            float q0 = qa[i][0] + bqv[0], q1 = qa[i][1] + bqv[1];
            float q2 = qa[i][2] + bqv[2], q3 = qa[i][3] + bqv[3];
            qv.x = (q0 > 0.f) ? 1.f + q0 : __expf(q0);
            qv.y = (q1 > 0.f) ? 1.f + q1 : __expf(q1);
            qv.z = (q2 > 0.f) ? 1.f + q2 : __expf(q2);
            qv.w = (q3 > 0.f) ? 1.f + q3 : __expf(q3);
            *(float4*)&Qg[(size_t)(n0 + r0 + i) * kHID + tx * 4] = qv;
        }
    }
    __syncthreads();
#pragma unroll
    for (int i = 0; i < 4; ++i) {
        int slot = t + 256 * i;
        int row = slot >> 4, cg = slot & 15;
        *(float4*)&sW[row * 68 + cg * 4] = *(const float4*)&Wk[(size_t)row * kHID + cg * 4];
    }
    __syncthreads();

    float ka[2][4];
#pragma unroll
    for (int i = 0; i < 2; ++i)
#pragma unroll
        for (int j = 0; j < 4; ++j) ka[i][j] = 0.f;
#pragma unroll 8
    for (int kk = 0; kk < 64; ++kk) {
        float4 b = *(float4*)&sW[kk * 68 + tx * 4];
        float a0 = sX[r0 * 68 + kk], a1 = sX[r1 * 68 + kk];
        ka[0][0] += a0 * b.x; ka[0][1] += a0 * b.y;
        ka[0][2] += a0 * b.z; ka[0][3] += a0 * b.w;
        ka[1][0] += a1 * b.x; ka[1][1] += a1 * b.y;
        ka[1][2] += a1 * b.z; ka[1][3] += a1 * b.w;
    }
    {
        float bkv[4];
#pragma unroll
        for (int j = 0; j < 4; ++j) bkv[j] = bk[tx * 4 + j];
#pragma unroll
        for (int i = 0; i < 2; ++i) {
            float4 kv;
            float k0v = ka[i][0] + bkv[0], k1v = ka[i][1] + bkv[1];
            float k2v = ka[i][2] + bkv[2], k3v = ka[i][3] + bkv[3];
            kv.x = (k0v > 0.f) ? 1.f + k0v : __expf(k0v);
            kv.y = (k1v > 0.f) ? 1.f + k1v : __expf(k1v);
            kv.z = (k2v > 0.f) ? 1.f + k2v : __expf(k2v);
            kv.w = (k3v > 0.f) ? 1.f + k3v : __expf(k3v);
            *(float4*)&Ktg[(size_t)(n0 + r0 + i) * kHID + tx * 4] = kv;
        }
    }
    __syncthreads();
#pragma unroll
    for (int i = 0; i < 3; ++i) {
        int slot = t + 256 * i;
        if (slot < 640) {
            int row = slot / 10, cg = slot % 10;
            *(float4*)&sW[row * 44 + cg * 4] = *(const float4*)&Wv[(size_t)row * 40 + cg * 4];
        }
    }
    __syncthreads();

    if (t < 160) {
        int txv = t % 10, tyv = t / 10;
        int vr0 = tyv * 2;
        float va[2][4];
#pragma unroll
        for (int i = 0; i < 2; ++i)
#pragma unroll
            for (int j = 0; j < 4; ++j) va[i][j] = 0.f;
#pragma unroll 8
        for (int kk = 0; kk < 64; ++kk) {
            float4 b = *(float4*)&sW[kk * 44 + txv * 4];
            float a0 = sX[vr0 * 68 + kk], a1 = sX[(vr0 + 1) * 68 + kk];
            va[0][0] += a0 * b.x; va[0][1] += a0 * b.y;
            va[0][2] += a0 * b.z; va[0][3] += a0 * b.w;
            va[1][0] += a1 * b.x; va[1][1] += a1 * b.y;
            va[1][2] += a1 * b.z; va[1][3] += a1 * b.w;
        }
        float bvv[4];
#pragma unroll
        for (int j = 0; j < 4; ++j) bvv[j] = bv[txv * 4 + j];
        float hw0 = hopwise[0];
#pragma unroll
        for (int i = 0; i < 2; ++i) {
            int row = vr0 + i;
            float4 vr;
            vr.x = va[i][0] + bvv[0]; vr.y = va[i][1] + bvv[1];
            vr.z = va[i][2] + bvv[2]; vr.w = va[i][3] + bvv[3];
            *(float4*)&Vg[(size_t)(n0 + row) * 40 + txv * 4] = vr;
            float4 hr;
            hr.x = vr.x * hw0; hr.y = vr.y * hw0; hr.z = vr.z * hw0; hr.w = vr.w * hw0;
            *(float4*)&hidden[(size_t)(n0 + row) * 40 + txv * 4] = hr;
        }
    }
}

// ---- hop 0, rank-1 with lane-local K (r9-proven), output in SLICE-MAJOR
//      layout: slice p row = 48 words (40 M bf16-pairs + 8 Kt f32).
//      Lane l owns canonical values [10l,10l+10) -> slice l>>3,
//      M words 5*(l&7)..+4, Kt word 40+(l&7). Inline hop-0 readout.
__global__ __launch_bounds__(256) void hop0_kernel(
    const int* __restrict__ ptr, const int* __restrict__ src, const float* __restrict__ wgt,
    const float* __restrict__ Ktin, const float* __restrict__ Vin,
    const float* __restrict__ Q,
    uint32_t* __restrict__ Mout,
    float* __restrict__ hidden, const float* __restrict__ gammas) {
    __shared__ float Ml[4][640];
    __shared__ float Ktl[4][64];
    __shared__ float Ql[4][64];
    int w = threadIdx.x >> 6;
    int l = threadIdx.x & 63;
    int n = blockIdx.x * 4 + w;
    int beg = ptr[n], end = ptr[n + 1];

    Ql[w][l] = Q[(size_t)n * 64 + l];

    int base_v = 10 * (l >> 4);
    int vidx = (l < 40) ? l : l - 40;

    float m[10];
#pragma unroll
    for (int i = 0; i < 10; ++i) m[i] = 0.f;
    float kacc = 0.f;

    auto edge = [&](float kl, float vv, float wv) {
        float kw = wv * kl;
        kacc += wv * kl;
#pragma unroll
        for (int c = 0; c < 10; ++c) {
            float vc = __shfl(vv, base_v + c, 64);
            m[c] += kw * vc;
        }
    };

    int e = beg;
    for (; e + 4 <= end; e += 4) {
        int s0 = src[e], s1 = src[e + 1], s2 = src[e + 2], s3 = src[e + 3];
        float w0 = wgt[e], w1 = wgt[e + 1], w2 = wgt[e + 2], w3 = wgt[e + 3];
        float ka = Ktin[(size_t)s0 * 64 + l], va = Vin[(size_t)s0 * 40 + vidx];
        float kb = Ktin[(size_t)s1 * 64 + l], vb = Vin[(size_t)s1 * 40 + vidx];
        float kc = Ktin[(size_t)s2 * 64 + l], vc = Vin[(size_t)s2 * 40 + vidx];
        float kd = Ktin[(size_t)s3 * 64 + l], vd = Vin[(size_t)s3 * 40 + vidx];
        edge(ka, va, w0); edge(kb, vb, w1); edge(kc, vc, w2); edge(kd, vd, w3);
    }
    for (; e < end; ++e) {
        int s0 = src[e];
        edge(Ktin[(size_t)s0 * 64 + l], Vin[(size_t)s0 * 40 + vidx], wgt[e]);
    }

    // write slice-major M1 + Kt1
    {
        int p = l >> 3, r = l & 7;
        uint32_t* row = Mout + (size_t)p * kMS + (size_t)n * 48;
        uint32_t* orow = row + r * 5;
        orow[0] = pack2(m[0], m[1]);
        orow[1] = pack2(m[2], m[3]);
        orow[2] = pack2(m[4], m[5]);
        orow[3] = pack2(m[6], m[7]);
        orow[4] = pack2(m[8], m[9]);
        row[40 + r] = __float_as_uint(kacc);
    }
    // stage canonical values 10l..10l+9 for inline readout
#pragma unroll
    for (int c = 0; c < 10; c += 2)
        *(float2*)&Ml[w][10 * l + c] = make_float2(m[c], m[c + 1]);
    Ktl[w][l] = kacc;
    __syncthreads();

    int tt = threadIdx.x;
    if (tt < 160) {
        int ww = tt / 40, o = tt % 40;
        int h = o / 10, j = o % 10;
        const float* q  = &Ql[ww][h * 16];
        const float* kk = &Ktl[ww][h * 16];
        const float* mm = &Ml[ww][h * 160 + j];
        float cd = kCST, hh = 0.f;
#pragma unroll
        for (int i = 0; i < 16; ++i) { cd += q[i] * kk[i]; hh += q[i] * mm[i * 10]; }
        int nn = blockIdx.x * 4 + ww;
        hidden[(size_t)nn * 40 + o] += gammas[h] * hh / cd;
    }
}

// ---- sliced hop (hops 1-2): blockIdx = g*8 + p. Slice p rows (192 B:
//      40 M-words + 8 Kt-f32) are L2-resident per XCD (3.84 MB).
//      Wave = 1 dest node, 8 edges in parallel (lane = 8*eo + r; lane loads
//      6 dwords at words r+8k). Butterfly shfl_xor reduce over eo.
//      nt stores for Mdst + partials. LAST: partials only.
template<bool LAST>
__global__ __launch_bounds__(256) void shop_kernel(
    const int* __restrict__ ptr, const int* __restrict__ src, const float* __restrict__ wgt,
    const uint32_t* __restrict__ Msrc, uint32_t* __restrict__ Mdst,
    const float* __restrict__ Q,
    float* __restrict__ HhBuf, float* __restrict__ CdBuf) {
    __shared__ float Qs[4][8];
    __shared__ float st[4][88];
    int t = threadIdx.x;
    int w = t >> 6, l = t & 63;
    int b = blockIdx.x;
    int p = b & 7, g = b >> 3;
    int n = g * 4 + w;
    int eo = l >> 3, r = l & 7;
    int beg = ptr[n], end = ptr[n + 1];
    const uint32_t* Mp = Msrc + (size_t)p * kMS;

    int h = p >> 1, ib = (p & 1) << 3;
    if (l < 8) Qs[w][l] = Q[(size_t)n * 64 + h * 16 + ib + l];   // same-wave LDS, no barrier

    float ml[5], mh[5];
#pragma unroll
    for (int k = 0; k < 5; ++k) { ml[k] = 0.f; mh[k] = 0.f; }
    float kt = 0.f;

    for (int e = beg; e < end; e += 8) {
        int ee = e + eo;
        if (ee < end) {
            int su = __builtin_nontemporal_load(&src[ee]);
            float wv = __builtin_nontemporal_load(&wgt[ee]);
            const uint32_t* row = Mp + (size_t)su * 48 + r;
            uint32_t a0 = row[0], a1 = row[8], a2 = row[16], a3 = row[24], a4 = row[32];
            uint32_t kv = row[40];
            ml[0] += wv * lo16(a0); mh[0] += wv * hi16(a0);
            ml[1] += wv * lo16(a1); mh[1] += wv * hi16(a1);
            ml[2] += wv * lo16(a2); mh[2] += wv * hi16(a2);
            ml[3] += wv * lo16(a3); mh[3] += wv * hi16(a3);
            ml[4] += wv * lo16(a4); mh[4] += wv * hi16(a4);
            kt += wv * __uint_as_float(kv);
        }
    }
    // butterfly reduce across eo-groups (lanes stride 8)
#pragma unroll
    for (int msk = 8; msk <= 32; msk <<= 1) {
#pragma unroll
        for (int k = 0; k < 5; ++k) {
            ml[k] += __shfl_xor(ml[k], msk, 64);
            mh[k] += __shfl_xor(mh[k], msk, 64);
        }
        kt += __shfl_xor(kt, msk, 64);
    }

    if constexpr (!LAST) {
        // lane l writes word l (k-slot = eo selects from registers)
        if (l < 40) {
            float lo = (eo == 0) ? ml[0] : (eo == 1) ? ml[1] : (eo == 2) ? ml[2]
                     : (eo == 3) ? ml[3] : ml[4];
            float hi = (eo == 0) ? mh[0] : (eo == 1) ? mh[1] : (eo == 2) ? mh[2]
                     : (eo == 3) ? mh[3] : mh[4];
            __builtin_nontemporal_store(pack2(lo, hi),
                &Mdst[(size_t)p * kMS + (size_t)n * 48 + l]);
        } else if (l < 48) {
            __builtin_nontemporal_store(__float_as_uint(kt),
                &Mdst[(size_t)p * kMS + (size_t)n * 48 + l]);
        }
    }
    // stage raw slice values for partial readout (lanes eo==0 hold totals too)
    if (l < 8) {
#pragma unroll
        for (int k = 0; k < 5; ++k) {
            st[w][2 * (r + 8 * k)]     = ml[k];
            st[w][2 * (r + 8 * k) + 1] = mh[k];
        }
        st[w][80 + r] = kt;
    }
    // same-wave LDS: program order guarantees visibility
    if (l < 10) {
        float hh = 0.f;
#pragma unroll
        for (int i = 0; i < 8; ++i) hh += Qs[w][i] * st[w][i * 10 + l];
        __builtin_nontemporal_store(hh, &HhBuf[((size_t)n * 8 + p) * 10 + l]);
    } else if (l == 10) {
        float cd = 0.f;
#pragma unroll
        for (int i = 0; i < 8; ++i) cd += Qs[w][i] * st[w][80 + i];
        __builtin_nontemporal_store(cd, &CdBuf[(size_t)n * 8 + p]);
    }
}

// ---- epilogue: pair slice partials, hidden += gamma*Hh/Cd.
//      LAST: keep hidden in LDS, fuse out = hidden@W_out + b_out.
template<bool LAST>
__global__ __launch_bounds__(256) void epi_kernel(
    const float* __restrict__ HhBuf, const float* __restrict__ CdBuf,
    const float* __restrict__ gam, float* __restrict__ hidden,
    const float* __restrict__ W_out, const float* __restrict__ b_out,
    float* __restrict__ out) {
    __shared__ float Hl[6][40];
    int t = threadIdx.x;
    int node = blockIdx.x * 6 + t / 40;
    int o = t % 40;
    bool act = (t < 240) && (node < kN);
    if (act) {
        int h = o / 10, j = o - h * 10;
        float hh = HhBuf[(size_t)node * 80 + (2 * h) * 10 + j]
                 + HhBuf[(size_t)node * 80 + (2 * h + 1) * 10 + j];
        float cd = CdBuf[(size_t)node * 8 + 2 * h] + CdBuf[(size_t)node * 8 + 2 * h + 1] + kCST;
        float val = hidden[(size_t)node * 40 + o] + gam[h] * hh / cd;
        if constexpr (!LAST) hidden[(size_t)node * 40 + o] = val;
        else Hl[t / 40][o] = val;
    }
    if constexpr (LAST) {
        __syncthreads();
        if (t < 60) {
            int s = t / 10, c = t - s * 10;
            int nn = blockIdx.x * 6 + s;
            if (nn < kN) {
                float acc = b_out[c];
#pragma unroll
                for (int i = 0; i < 40; ++i) acc += Hl[s][i] * W_out[i * 10 + c];
                out[(size_t)nn * 10 + c] = acc;
            }
        }
    }
}

extern "C" void kernel_launch(void* const* d_in, const int* in_sizes, int n_in,
                              void* d_out, int out_size, void* d_ws, size_t ws_size,
                              hipStream_t stream) {
    const float* feat   = (const float*)d_in[0];
    const int*   ei     = (const int*)d_in[1];
    const float* W_in   = (const float*)d_in[2];
    const float* b_in   = (const float*)d_in[3];
    const float* Wq     = (const float*)d_in[4];
    const float* bq     = (const float*)d_in[5];
    const float* Wk     = (const float*)d_in[6];
    const float* bk     = (const float*)d_in[7];
    const float* Wv     = (const float*)d_in[8];
    const float* bv     = (const float*)d_in[9];
    const float* W_out  = (const float*)d_in[10];
    const float* b_out  = (const float*)d_in[11];
    const float* hopwise= (const float*)d_in[12];
    const float* temp   = (const float*)d_in[13];
    float* out = (float*)d_out;

    char* ws = (char*)d_ws;
    size_t off = 0;
    auto alloc = [&](size_t bytes) -> void* {
        void* p = ws + off;
        off += (bytes + 255) & ~(size_t)255;
        return p;
    };
    int*      deg    = (int*)alloc((size_t)kN * 4);
    int*      cursor = (int*)alloc((size_t)kN * 4);
    int*      ptr    = (int*)alloc((size_t)(kN + 1) * 4);
    int*      partial= (int*)alloc((size_t)kNB * 4);
    int*      offs   = (int*)alloc((size_t)kNB * 4);
    int*      csrc   = (int*)alloc((size_t)kET * 4);
    float*    cwgt   = (float*)alloc((size_t)kET * 4);
    float*    Q      = (float*)alloc((size_t)kN * kHID * 4);
    float*    Kt0    = (float*)alloc((size_t)kN * kHID * 4);
    float*    Vg     = (float*)alloc((size_t)kN * kH * kC * 4);
    float*    hidden = (float*)alloc((size_t)kN * kH * kC * 4);
    float*    gammas = (float*)alloc(64);
    float*    HhBuf  = (float*)alloc((size_t)kN * 80 * 4);
    float*    CdBuf  = (float*)alloc((size_t)kN * 8 * 4);
    uint32_t* Ms1    = (uint32_t*)alloc((size_t)8 * kMS * 4);
    uint32_t* Ms2    = (uint32_t*)alloc((size_t)8 * kMS * 4);
    (void)ws_size; (void)in_sizes; (void)n_in; (void)out_size;

    // deg & cursor are adjacent in ws: one memset covers both
    size_t deg_span = (size_t)((char*)cursor - (char*)deg) + (size_t)kN * 4;
    hipMemsetAsync(deg, 0, deg_span, stream);

    deg_kernel<<<(kET + 255) / 256, 256, 0, stream>>>(ei, deg);
    degsum_kernel<<<kNB, 256, 0, stream>>>(deg, partial);
    midscan_kernel<<<1, 128, 0, stream>>>(partial, offs, hopwise, temp, gammas);
    ptrw_kernel<<<kNB, 256, 0, stream>>>(deg, offs, ptr);
    scatter_kernel<<<(kET + 255) / 256, 256, 0, stream>>>(ei, deg, ptr, cursor, csrc, cwgt);
    proj_kernel<<<kN / kBN, 256, 0, stream>>>(feat, W_in, b_in, Wq, bq, Wk, bk, Wv, bv,
                                              hopwise, Q, Kt0, hidden, Vg);
    // hop 0 (rank-1 factors): Kt0,Vg -> Ms1 (slice-major, Kt fused) + inline readout
    hop0_kernel<<<kN / 4, 256, 0, stream>>>(ptr, csrc, cwgt, Kt0, Vg, Q, Ms1, hidden,
                                            gammas + 0);
    const int SG = (kN / 4) * 8;           // 5000 dest-groups x 8 slices
    const int EG = (kN + 5) / 6;
    // hop 1: Ms1 -> Ms2 + partials
    shop_kernel<false><<<SG, 256, 0, stream>>>(ptr, csrc, cwgt, Ms1, Ms2, Q, HhBuf, CdBuf);
    epi_kernel<false><<<EG, 256, 0, stream>>>(HhBuf, CdBuf, gammas + 4, hidden, W_out, b_out, out);
    // hop 2 (last): partials only + fused output GEMM in epilogue
    shop_kernel<true><<<SG, 256, 0, stream>>>(ptr, csrc, cwgt, Ms2, Ms1, Q, HhBuf, CdBuf);
    epi_kernel<true><<<EG, 256, 0, stream>>>(HhBuf, CdBuf, gammas + 8, hidden, W_out, b_out, out);
}

// Round 11
// 179.540 us; speedup vs baseline: 1.6057x; 1.6057x over previous
//
#include <hip/hip_runtime.h>
#include <stdint.h>

// Problem constants (match reference)
#define kN   20000
#define kE   160000
#define kET  (kN + kE)   // edges incl self loops = 180000
#define kF   256
#define kHID 64
#define kH   4
#define kHC  16
#define kC   10
#define kK   3
#define kCST 1e-5f
#define kBN  32          // nodes per proj block (625 blocks)
#define kNB  ((kN + 255) / 256)   // 79 partial-scan blocks

__device__ __forceinline__ uint16_t f2bf(float x) {
    uint32_t u = __float_as_uint(x);
    u += 0x7fffu + ((u >> 16) & 1u);   // round-to-nearest-even
    return (uint16_t)(u >> 16);
}
__device__ __forceinline__ float lo16(uint32_t p) { return __uint_as_float(p << 16); }
__device__ __forceinline__ float hi16(uint32_t p) { return __uint_as_float(p & 0xffff0000u); }
__device__ __forceinline__ uint32_t pack2(float a, float b) {
    return ((uint32_t)f2bf(b) << 16) | (uint32_t)f2bf(a);
}

// ---- degree histogram over col (incl self loops) ----
__global__ void deg_kernel(const int* __restrict__ ei, int* __restrict__ deg) {
    int e = blockIdx.x * blockDim.x + threadIdx.x;
    if (e >= kET) return;
    int c = (e < kE) ? ei[kE + e] : (e - kE);
    atomicAdd(&deg[c], 1);
}

// ---- parallel scan stage 1: per-block (256) sums of deg ----
__global__ __launch_bounds__(256) void degsum_kernel(const int* __restrict__ deg,
                                                     int* __restrict__ partial) {
    __shared__ int sw[4];
    int t = threadIdx.x;
    int idx = blockIdx.x * 256 + t;
    int v = (idx < kN) ? deg[idx] : 0;
#pragma unroll
    for (int off = 32; off >= 1; off >>= 1) v += __shfl_xor(v, off, 64);
    if ((t & 63) == 0) sw[t >> 6] = v;
    __syncthreads();
    if (t == 0) partial[blockIdx.x] = sw[0] + sw[1] + sw[2] + sw[3];
}

// ---- stage 2: scan the 79 partials (exclusive) + gammas ----
__global__ __launch_bounds__(128) void midscan_kernel(
    const int* __restrict__ partial, int* __restrict__ offsets,
    const float* __restrict__ hopwise, const float* __restrict__ temp,
    float* __restrict__ gammas) {
    __shared__ int ws0;
    int t = threadIdx.x;
    int v = (t < kNB) ? partial[t] : 0;
    int incl = v;
#pragma unroll
    for (int off = 1; off < 64; off <<= 1) {
        int u = __shfl_up(incl, off, 64);
        if ((t & 63) >= off) incl += u;
    }
    if (t == 63) ws0 = incl;
    __syncthreads();
    int add = (t >= 64) ? ws0 : 0;
    if (t < kNB) offsets[t] = add + incl - v;
    if (t == 0) {
        for (int k = 1; k <= kK; ++k) {
            float mx = -1e30f;
            for (int h = 0; h < kH; ++h) mx = fmaxf(mx, temp[h * (kK + 1) + k]);
            float ex[kH]; float sum = 0.f;
            for (int h = 0; h < kH; ++h) { ex[h] = __expf(temp[h * (kK + 1) + k] - mx); sum += ex[h]; }
            for (int h = 0; h < kH; ++h) gammas[(k - 1) * kH + h] = hopwise[k] * ex[h] / sum;
        }
    }
}

// ---- stage 3: ptr[idx] = offsets[b] + in-block exclusive prefix ----
__global__ __launch_bounds__(256) void ptrw_kernel(const int* __restrict__ deg,
                                                   const int* __restrict__ offsets,
                                                   int* __restrict__ ptr) {
    __shared__ int sw[4];
    int t = threadIdx.x;
    int idx = blockIdx.x * 256 + t;
    int v = (idx < kN) ? deg[idx] : 0;
    int incl = v;
#pragma unroll
    for (int off = 1; off < 64; off <<= 1) {
        int u = __shfl_up(incl, off, 64);
        if ((t & 63) >= off) incl += u;
    }
    int wid = t >> 6;
    if ((t & 63) == 63) sw[wid] = incl;
    __syncthreads();
    int wadd = 0;
    for (int j = 0; j < 4; ++j) wadd += (j < wid) ? sw[j] : 0;
    int excl = offsets[blockIdx.x] + wadd + incl - v;
    if (idx < kN) ptr[idx] = excl;
    if (idx == kN - 1) ptr[kN] = excl + v;
}

// ---- CSR (by col) build: scatter (row, norm); norm from deg via rsqrt ----
__global__ void scatter_kernel(const int* __restrict__ ei, const int* __restrict__ deg,
                               const int* __restrict__ ptr, int* __restrict__ cursor,
                               int* __restrict__ src, float* __restrict__ wgt) {
    int e = blockIdx.x * blockDim.x + threadIdx.x;
    if (e >= kET) return;
    int r, c;
    if (e < kE) { r = ei[e]; c = ei[kE + e]; } else { r = c = e - kE; }
    float wv = rsqrtf((float)deg[r]) * rsqrtf((float)deg[c]);
    int pos = ptr[c] + atomicAdd(&cursor[c], 1);
    src[pos] = r;
    wgt[pos] = wv;
}

// ---- fused projections, 32 nodes/block x 625 blocks (r9-proven). ----
__global__ __launch_bounds__(256) void proj_kernel(
    const float* __restrict__ feat, const float* __restrict__ W_in, const float* __restrict__ b_in,
    const float* __restrict__ Wq, const float* __restrict__ bq,
    const float* __restrict__ Wk, const float* __restrict__ bk,
    const float* __restrict__ Wv, const float* __restrict__ bv,
    const float* __restrict__ hopwise,
    float* __restrict__ Qg, float* __restrict__ Ktg, float* __restrict__ hidden,
    float* __restrict__ Vg) {
    __shared__ float sF[kBN * 68];   // feat k-tile
    __shared__ float sW[64 * 68];    // W_in tile -> Wq -> Wk -> Wv
    __shared__ float sX[kBN * 68];   // x

    int t = threadIdx.x;
    int tx = t & 15, ty = t >> 4;    // 16 x 16 thread grid
    int n0 = blockIdx.x * kBN;
    int r0 = ty * 2, r1 = ty * 2 + 1;

    float acc[2][4];
#pragma unroll
    for (int i = 0; i < 2; ++i)
#pragma unroll
        for (int j = 0; j < 4; ++j) acc[i][j] = 0.f;

    for (int ks = 0; ks < 4; ++ks) {
        int k0 = ks * 64;
#pragma unroll
        for (int i = 0; i < 2; ++i) {
            int slot = t + 256 * i;
            int row = slot >> 4, cg = slot & 15;
            *(float4*)&sF[row * 68 + cg * 4] =
                *(const float4*)&feat[(size_t)(n0 + row) * kF + k0 + cg * 4];
        }
#pragma unroll
        for (int i = 0; i < 4; ++i) {
            int slot = t + 256 * i;
            int row = slot >> 4, cg = slot & 15;
            *(float4*)&sW[row * 68 + cg * 4] =
                *(const float4*)&W_in[(size_t)(k0 + row) * kHID + cg * 4];
        }
        __syncthreads();
#pragma unroll 8
        for (int kk = 0; kk < 64; ++kk) {
            float4 b = *(float4*)&sW[kk * 68 + tx * 4];
            float a0 = sF[r0 * 68 + kk], a1 = sF[r1 * 68 + kk];
            acc[0][0] += a0 * b.x; acc[0][1] += a0 * b.y;
            acc[0][2] += a0 * b.z; acc[0][3] += a0 * b.w;
            acc[1][0] += a1 * b.x; acc[1][1] += a1 * b.y;
            acc[1][2] += a1 * b.z; acc[1][3] += a1 * b.w;
        }
        __syncthreads();
    }
    {
        float bb[4];
#pragma unroll
        for (int j = 0; j < 4; ++j) bb[j] = b_in[tx * 4 + j];
#pragma unroll
        for (int i = 0; i < 2; ++i) {
            float4 xr;
            xr.x = fmaxf(acc[i][0] + bb[0], 0.f);
            xr.y = fmaxf(acc[i][1] + bb[1], 0.f);
            xr.z = fmaxf(acc[i][2] + bb[2], 0.f);
            xr.w = fmaxf(acc[i][3] + bb[3], 0.f);
            *(float4*)&sX[(r0 + i) * 68 + tx * 4] = xr;
        }
    }
#pragma unroll
    for (int i = 0; i < 4; ++i) {
        int slot = t + 256 * i;
        int row = slot >> 4, cg = slot & 15;
        *(float4*)&sW[row * 68 + cg * 4] = *(const float4*)&Wq[(size_t)row * kHID + cg * 4];
    }
    __syncthreads();

    float qa[2][4];
#pragma unroll
    for (int i = 0; i < 2; ++i)
#pragma unroll
        for (int j = 0; j < 4; ++j) qa[i][j] = 0.f;
#pragma unroll 8
    for (int kk = 0; kk < 64; ++kk) {
        float4 b = *(float4*)&sW[kk * 68 + tx * 4];
        float a0 = sX[r0 * 68 + kk], a1 = sX[r1 * 68 + kk];
        qa[0][0] += a0 * b.x; qa[0][1] += a0 * b.y;
        qa[0][2] += a0 * b.z; qa[0][3] += a0 * b.w;
        qa[1][0] += a1 * b.x; qa[1][1] += a1 * b.y;
        qa[1][2] += a1 * b.z; qa[1][3] += a1 * b.w;
    }
    {
        float bqv[4];
#pragma unroll
        for (int j = 0; j < 4; ++j) bqv[j] = bq[tx * 4 + j];
#pragma unroll
        for (int i = 0; i < 2; ++i) {
            float4 qv;
            float q0 = qa[i][0] + bqv[0], q1 = qa[i][1] + bqv[1];
            float q2 = qa[i][2] + bqv[2], q3 = qa[i][3] + bqv[3];
            qv.x = (q0 > 0.f) ? 1.f + q0 : __expf(q0);
            qv.y = (q1 > 0.f) ? 1.f + q1 : __expf(q1);
            qv.z = (q2 > 0.f) ? 1.f + q2 : __expf(q2);
            qv.w = (q3 > 0.f) ? 1.f + q3 : __expf(q3);
            *(float4*)&Qg[(size_t)(n0 + r0 + i) * kHID + tx * 4] = qv;
        }
    }
    __syncthreads();
#pragma unroll
    for (int i = 0; i < 4; ++i) {
        int slot = t + 256 * i;
        int row = slot >> 4, cg = slot & 15;
        *(float4*)&sW[row * 68 + cg * 4] = *(const float4*)&Wk[(size_t)row * kHID + cg * 4];
    }
    __syncthreads();

    float ka[2][4];
#pragma unroll
    for (int i = 0; i < 2; ++i)
#pragma unroll
        for (int j = 0; j < 4; ++j) ka[i][j] = 0.f;
#pragma unroll 8
    for (int kk = 0; kk < 64; ++kk) {
        float4 b = *(float4*)&sW[kk * 68 + tx * 4];
        float a0 = sX[r0 * 68 + kk], a1 = sX[r1 * 68 + kk];
        ka[0][0] += a0 * b.x; ka[0][1] += a0 * b.y;
        ka[0][2] += a0 * b.z; ka[0][3] += a0 * b.w;
        ka[1][0] += a1 * b.x; ka[1][1] += a1 * b.y;
        ka[1][2] += a1 * b.z; ka[1][3] += a1 * b.w;
    }
    {
        float bkv[4];
#pragma unroll
        for (int j = 0; j < 4; ++j) bkv[j] = bk[tx * 4 + j];
#pragma unroll
        for (int i = 0; i < 2; ++i) {
            float4 kv;
            float k0v = ka[i][0] + bkv[0], k1v = ka[i][1] + bkv[1];
            float k2v = ka[i][2] + bkv[2], k3v = ka[i][3] + bkv[3];
            kv.x = (k0v > 0.f) ? 1.f + k0v : __expf(k0v);
            kv.y = (k1v > 0.f) ? 1.f + k1v : __expf(k1v);
            kv.z = (k2v > 0.f) ? 1.f + k2v : __expf(k2v);
            kv.w = (k3v > 0.f) ? 1.f + k3v : __expf(k3v);
            *(float4*)&Ktg[(size_t)(n0 + r0 + i) * kHID + tx * 4] = kv;
        }
    }
    __syncthreads();
#pragma unroll
    for (int i = 0; i < 3; ++i) {
        int slot = t + 256 * i;
        if (slot < 640) {
            int row = slot / 10, cg = slot % 10;
            *(float4*)&sW[row * 44 + cg * 4] = *(const float4*)&Wv[(size_t)row * 40 + cg * 4];
        }
    }
    __syncthreads();

    if (t < 160) {
        int txv = t % 10, tyv = t / 10;
        int vr0 = tyv * 2;
        float va[2][4];
#pragma unroll
        for (int i = 0; i < 2; ++i)
#pragma unroll
            for (int j = 0; j < 4; ++j) va[i][j] = 0.f;
#pragma unroll 8
        for (int kk = 0; kk < 64; ++kk) {
            float4 b = *(float4*)&sW[kk * 44 + txv * 4];
            float a0 = sX[vr0 * 68 + kk], a1 = sX[(vr0 + 1) * 68 + kk];
            va[0][0] += a0 * b.x; va[0][1] += a0 * b.y;
            va[0][2] += a0 * b.z; va[0][3] += a0 * b.w;
            va[1][0] += a1 * b.x; va[1][1] += a1 * b.y;
            va[1][2] += a1 * b.z; va[1][3] += a1 * b.w;
        }
        float bvv[4];
#pragma unroll
        for (int j = 0; j < 4; ++j) bvv[j] = bv[txv * 4 + j];
        float hw0 = hopwise[0];
#pragma unroll
        for (int i = 0; i < 2; ++i) {
            int row = vr0 + i;
            float4 vr;
            vr.x = va[i][0] + bvv[0]; vr.y = va[i][1] + bvv[1];
            vr.z = va[i][2] + bvv[2]; vr.w = va[i][3] + bvv[3];
            *(float4*)&Vg[(size_t)(n0 + row) * 40 + txv * 4] = vr;
            float4 hr;
            hr.x = vr.x * hw0; hr.y = vr.y * hw0; hr.z = vr.z * hw0; hr.w = vr.w * hw0;
            *(float4*)&hidden[(size_t)(n0 + row) * 40 + txv * 4] = hr;
        }
    }
}

// ---- hop 0, rank-1 with lane-local K (r9-proven), now 8-edge unroll +
//      NT loads for streamed src/wgt. Lane l owns canonical values
//      [10l,10l+10): K factor = Kt[s][l] (own load), V via 10 bpermutes.
__global__ __launch_bounds__(256) void hop0_kernel(
    const int* __restrict__ ptr, const int* __restrict__ src, const float* __restrict__ wgt,
    const float* __restrict__ Ktin, const float* __restrict__ Vin,
    const float* __restrict__ Q,
    uint16_t* __restrict__ Mout, float* __restrict__ Ktout,
    float* __restrict__ hidden, const float* __restrict__ gammas) {
    __shared__ float Ml[4][640];
    __shared__ float Ktl[4][64];
    __shared__ float Ql[4][64];
    int w = threadIdx.x >> 6;
    int l = threadIdx.x & 63;
    int n = blockIdx.x * 4 + w;
    int beg = ptr[n], end = ptr[n + 1];

    Ql[w][l] = Q[(size_t)n * 64 + l];

    int base_v = 10 * (l >> 4);
    int vidx = (l < 40) ? l : l - 40;

    float m[10];
#pragma unroll
    for (int i = 0; i < 10; ++i) m[i] = 0.f;
    float kacc = 0.f;

    auto edge = [&](float kl, float vv, float wv) {
        float kw = wv * kl;
        kacc += wv * kl;
#pragma unroll
        for (int c = 0; c < 10; ++c) {
            float vc = __shfl(vv, base_v + c, 64);
            m[c] += kw * vc;
        }
    };

    int e = beg;
    for (; e + 8 <= end; e += 8) {
        int s0 = __builtin_nontemporal_load(&src[e]);
        int s1 = __builtin_nontemporal_load(&src[e + 1]);
        int s2 = __builtin_nontemporal_load(&src[e + 2]);
        int s3 = __builtin_nontemporal_load(&src[e + 3]);
        int s4 = __builtin_nontemporal_load(&src[e + 4]);
        int s5 = __builtin_nontemporal_load(&src[e + 5]);
        int s6 = __builtin_nontemporal_load(&src[e + 6]);
        int s7 = __builtin_nontemporal_load(&src[e + 7]);
        float w0 = __builtin_nontemporal_load(&wgt[e]);
        float w1 = __builtin_nontemporal_load(&wgt[e + 1]);
        float w2 = __builtin_nontemporal_load(&wgt[e + 2]);
        float w3 = __builtin_nontemporal_load(&wgt[e + 3]);
        float w4 = __builtin_nontemporal_load(&wgt[e + 4]);
        float w5 = __builtin_nontemporal_load(&wgt[e + 5]);
        float w6 = __builtin_nontemporal_load(&wgt[e + 6]);
        float w7 = __builtin_nontemporal_load(&wgt[e + 7]);
        float ka = Ktin[(size_t)s0 * 64 + l], va = Vin[(size_t)s0 * 40 + vidx];
        float kb = Ktin[(size_t)s1 * 64 + l], vb = Vin[(size_t)s1 * 40 + vidx];
        float kc = Ktin[(size_t)s2 * 64 + l], vc = Vin[(size_t)s2 * 40 + vidx];
        float kd = Ktin[(size_t)s3 * 64 + l], vd = Vin[(size_t)s3 * 40 + vidx];
        float ke = Ktin[(size_t)s4 * 64 + l], ve = Vin[(size_t)s4 * 40 + vidx];
        float kf = Ktin[(size_t)s5 * 64 + l], vf = Vin[(size_t)s5 * 40 + vidx];
        float kg = Ktin[(size_t)s6 * 64 + l], vg = Vin[(size_t)s6 * 40 + vidx];
        float kh = Ktin[(size_t)s7 * 64 + l], vh = Vin[(size_t)s7 * 40 + vidx];
        edge(ka, va, w0); edge(kb, vb, w1); edge(kc, vc, w2); edge(kd, vd, w3);
        edge(ke, ve, w4); edge(kf, vf, w5); edge(kg, vg, w6); edge(kh, vh, w7);
    }
    if (e + 4 <= end) {
        int s0 = src[e], s1 = src[e + 1], s2 = src[e + 2], s3 = src[e + 3];
        float w0 = wgt[e], w1 = wgt[e + 1], w2 = wgt[e + 2], w3 = wgt[e + 3];
        float ka = Ktin[(size_t)s0 * 64 + l], va = Vin[(size_t)s0 * 40 + vidx];
        float kb = Ktin[(size_t)s1 * 64 + l], vb = Vin[(size_t)s1 * 40 + vidx];
        float kc = Ktin[(size_t)s2 * 64 + l], vc = Vin[(size_t)s2 * 40 + vidx];
        float kd = Ktin[(size_t)s3 * 64 + l], vd = Vin[(size_t)s3 * 40 + vidx];
        edge(ka, va, w0); edge(kb, vb, w1); edge(kc, vc, w2); edge(kd, vd, w3);
        e += 4;
    }
    for (; e < end; ++e) {
        int s0 = src[e];
        edge(Ktin[(size_t)s0 * 64 + l], Vin[(size_t)s0 * 40 + vidx], wgt[e]);
    }

    // write M1 (canonical words 5l..5l+4) + Kt1
    {
        uint32_t* orow = (uint32_t*)Mout + (size_t)n * 320 + 5 * l;
        orow[0] = pack2(m[0], m[1]);
        orow[1] = pack2(m[2], m[3]);
        orow[2] = pack2(m[4], m[5]);
        orow[3] = pack2(m[6], m[7]);
        orow[4] = pack2(m[8], m[9]);
        Ktout[(size_t)n * 64 + l] = kacc;
    }
#pragma unroll
    for (int c = 0; c < 10; c += 2)
        *(float2*)&Ml[w][10 * l + c] = make_float2(m[c], m[c + 1]);
    Ktl[w][l] = kacc;
    __syncthreads();

    int tt = threadIdx.x;
    if (tt < 160) {
        int ww = tt / 40, o = tt % 40;
        int h = o / 10, j = o % 10;
        const float* q  = &Ql[ww][h * 16];
        const float* kk = &Ktl[ww][h * 16];
        const float* mm = &Ml[ww][h * 160 + j];
        float cd = kCST, hh = 0.f;
#pragma unroll
        for (int i = 0; i < 16; ++i) { cd += q[i] * kk[i]; hh += q[i] * mm[i * 10]; }
        int nn = blockIdx.x * 4 + ww;
        hidden[(size_t)nn * 40 + o] += gammas[h] * hh / cd;
    }
}

// ---- hops 1-2, wave-per-node (r4/r9-proven) + NT hints: NT loads for
//      once-streamed src/wgt/Q; NT stores for Mout/Ktout (consumed next
//      kernel, 7/8 cross-XCD) to keep Min rows L2-resident.
template<bool LAST>
__global__ __launch_bounds__(256) void hop2_kernel(
    const int* __restrict__ ptr, const int* __restrict__ src, const float* __restrict__ wgt,
    const uint16_t* __restrict__ Min, uint16_t* __restrict__ Mout,
    const float* __restrict__ Ktin, float* __restrict__ Ktout,
    const float* __restrict__ Q, float* __restrict__ hidden,
    const float* __restrict__ gammas,
    const float* __restrict__ W_out, const float* __restrict__ b_out,
    float* __restrict__ out) {
    __shared__ float Ml[4][640];
    __shared__ float Ktl[4][64];
    __shared__ float Ql[4][64];
    __shared__ float Hl[4][40];
    int w = threadIdx.x >> 6;     // node slot
    int l = threadIdx.x & 63;     // lane
    int n = blockIdx.x * 4 + w;
    int beg = ptr[n], end = ptr[n + 1];
    const uint32_t* Mw = (const uint32_t*)Min;

    Ql[w][l] = __builtin_nontemporal_load(&Q[(size_t)n * 64 + l]);

    float m0=0,m1=0,m2=0,m3=0,m4=0,m5=0,m6=0,m7=0,m8=0,m9=0;
    float kacc = 0.f;
    int e = beg;
    for (; e + 4 <= end; e += 4) {
        int s0 = __builtin_nontemporal_load(&src[e]);
        int s1 = __builtin_nontemporal_load(&src[e + 1]);
        int s2 = __builtin_nontemporal_load(&src[e + 2]);
        int s3 = __builtin_nontemporal_load(&src[e + 3]);
        float w0 = __builtin_nontemporal_load(&wgt[e]);
        float w1 = __builtin_nontemporal_load(&wgt[e + 1]);
        float w2 = __builtin_nontemporal_load(&wgt[e + 2]);
        float w3 = __builtin_nontemporal_load(&wgt[e + 3]);
        const uint32_t* p0 = Mw + (size_t)s0 * 320 + l;
        const uint32_t* p1 = Mw + (size_t)s1 * 320 + l;
        const uint32_t* p2 = Mw + (size_t)s2 * 320 + l;
        const uint32_t* p3 = Mw + (size_t)s3 * 320 + l;
        uint32_t a0 = p0[0], a1 = p0[64], a2 = p0[128], a3 = p0[192], a4 = p0[256];
        uint32_t b0 = p1[0], b1 = p1[64], b2 = p1[128], b3 = p1[192], b4 = p1[256];
        uint32_t c0 = p2[0], c1 = p2[64], c2 = p2[128], c3 = p2[192], c4 = p2[256];
        uint32_t d0 = p3[0], d1 = p3[64], d2 = p3[128], d3 = p3[192], d4 = p3[256];
        float ka = Ktin[(size_t)s0 * 64 + l], kb = Ktin[(size_t)s1 * 64 + l];
        float kc = Ktin[(size_t)s2 * 64 + l], kd = Ktin[(size_t)s3 * 64 + l];
        m0 += w0 * lo16(a0); m1 += w0 * hi16(a0);
        m2 += w0 * lo16(a1); m3 += w0 * hi16(a1);
        m4 += w0 * lo16(a2); m5 += w0 * hi16(a2);
        m6 += w0 * lo16(a3); m7 += w0 * hi16(a3);
        m8 += w0 * lo16(a4); m9 += w0 * hi16(a4);
        m0 += w1 * lo16(b0); m1 += w1 * hi16(b0);
        m2 += w1 * lo16(b1); m3 += w1 * hi16(b1);
        m4 += w1 * lo16(b2); m5 += w1 * hi16(b2);
        m6 += w1 * lo16(b3); m7 += w1 * hi16(b3);
        m8 += w1 * lo16(b4); m9 += w1 * hi16(b4);
        m0 += w2 * lo16(c0); m1 += w2 * hi16(c0);
        m2 += w2 * lo16(c1); m3 += w2 * hi16(c1);
        m4 += w2 * lo16(c2); m5 += w2 * hi16(c2);
        m6 += w2 * lo16(c3); m7 += w2 * hi16(c3);
        m8 += w2 * lo16(c4); m9 += w2 * hi16(c4);
        m0 += w3 * lo16(d0); m1 += w3 * hi16(d0);
        m2 += w3 * lo16(d1); m3 += w3 * hi16(d1);
        m4 += w3 * lo16(d2); m5 += w3 * hi16(d2);
        m6 += w3 * lo16(d3); m7 += w3 * hi16(d3);
        m8 += w3 * lo16(d4); m9 += w3 * hi16(d4);
        kacc += w0 * ka + w1 * kb + w2 * kc + w3 * kd;
    }
    for (; e + 2 <= end; e += 2) {
        int s0 = src[e], s1 = src[e + 1];
        float w0 = wgt[e], w1 = wgt[e + 1];
        const uint32_t* p0 = Mw + (size_t)s0 * 320 + l;
        const uint32_t* p1 = Mw + (size_t)s1 * 320 + l;
        uint32_t a0 = p0[0], a1 = p0[64], a2 = p0[128], a3 = p0[192], a4 = p0[256];
        uint32_t b0 = p1[0], b1 = p1[64], b2 = p1[128], b3 = p1[192], b4 = p1[256];
        float ka = Ktin[(size_t)s0 * 64 + l], kb = Ktin[(size_t)s1 * 64 + l];
        m0 += w0 * lo16(a0); m1 += w0 * hi16(a0);
        m2 += w0 * lo16(a1); m3 += w0 * hi16(a1);
        m4 += w0 * lo16(a2); m5 += w0 * hi16(a2);
        m6 += w0 * lo16(a3); m7 += w0 * hi16(a3);
        m8 += w0 * lo16(a4); m9 += w0 * hi16(a4);
        m0 += w1 * lo16(b0); m1 += w1 * hi16(b0);
        m2 += w1 * lo16(b1); m3 += w1 * hi16(b1);
        m4 += w1 * lo16(b2); m5 += w1 * hi16(b2);
        m6 += w1 * lo16(b3); m7 += w1 * hi16(b3);
        m8 += w1 * lo16(b4); m9 += w1 * hi16(b4);
        kacc += w0 * ka + w1 * kb;
    }
    if (e < end) {
        int s0 = src[e];
        float w0 = wgt[e];
        const uint32_t* p0 = Mw + (size_t)s0 * 320 + l;
        uint32_t a0 = p0[0], a1 = p0[64], a2 = p0[128], a3 = p0[192], a4 = p0[256];
        float ka = Ktin[(size_t)s0 * 64 + l];
        m0 += w0 * lo16(a0); m1 += w0 * hi16(a0);
        m2 += w0 * lo16(a1); m3 += w0 * hi16(a1);
        m4 += w0 * lo16(a2); m5 += w0 * hi16(a2);
        m6 += w0 * lo16(a3); m7 += w0 * hi16(a3);
        m8 += w0 * lo16(a4); m9 += w0 * hi16(a4);
        kacc += w0 * ka;
    }

    // stage to LDS (word (l+64c) holds values 2(l+64c), 2(l+64c)+1)
    *(float2*)&Ml[w][2 * l]         = make_float2(m0, m1);
    *(float2*)&Ml[w][2 * (l + 64)]  = make_float2(m2, m3);
    *(float2*)&Ml[w][2 * (l + 128)] = make_float2(m4, m5);
    *(float2*)&Ml[w][2 * (l + 192)] = make_float2(m6, m7);
    *(float2*)&Ml[w][2 * (l + 256)] = make_float2(m8, m9);
    Ktl[w][l] = kacc;
    if constexpr (!LAST) {
        uint32_t* orow = (uint32_t*)Mout + (size_t)n * 320 + l;
        __builtin_nontemporal_store(pack2(m0, m1), orow);
        __builtin_nontemporal_store(pack2(m2, m3), orow + 64);
        __builtin_nontemporal_store(pack2(m4, m5), orow + 128);
        __builtin_nontemporal_store(pack2(m6, m7), orow + 192);
        __builtin_nontemporal_store(pack2(m8, m9), orow + 256);
        __builtin_nontemporal_store(kacc, &Ktout[(size_t)n * 64 + l]);
    }
    __syncthreads();

    int tt = threadIdx.x;
    if (tt < 160) {
        int ww = tt / 40, o = tt % 40;
        int h = o / 10, j = o % 10;
        const float* q  = &Ql[ww][h * 16];
        const float* kk = &Ktl[ww][h * 16];
        const float* mm = &Ml[ww][h * 160 + j];
        float cd = kCST, hh = 0.f;
#pragma unroll
        for (int i = 0; i < 16; ++i) { cd += q[i] * kk[i]; hh += q[i] * mm[i * 10]; }
        int nn = blockIdx.x * 4 + ww;
        float val = hidden[(size_t)nn * 40 + o] + gammas[h] * hh / cd;
        if constexpr (!LAST) hidden[(size_t)nn * 40 + o] = val;
        else Hl[ww][o] = val;
    }
    if constexpr (LAST) {
        __syncthreads();
        if (tt < 40) {
            int ww = tt / 10, c = tt % 10;
            float acc = b_out[c];
#pragma unroll
            for (int i = 0; i < 40; ++i) acc += Hl[ww][i] * W_out[i * 10 + c];
            out[(size_t)(blockIdx.x * 4 + ww) * 10 + c] = acc;
        }
    }
}

extern "C" void kernel_launch(void* const* d_in, const int* in_sizes, int n_in,
                              void* d_out, int out_size, void* d_ws, size_t ws_size,
                              hipStream_t stream) {
    const float* feat   = (const float*)d_in[0];
    const int*   ei     = (const int*)d_in[1];
    const float* W_in   = (const float*)d_in[2];
    const float* b_in   = (const float*)d_in[3];
    const float* Wq     = (const float*)d_in[4];
    const float* bq     = (const float*)d_in[5];
    const float* Wk     = (const float*)d_in[6];
    const float* bk     = (const float*)d_in[7];
    const float* Wv     = (const float*)d_in[8];
    const float* bv     = (const float*)d_in[9];
    const float* W_out  = (const float*)d_in[10];
    const float* b_out  = (const float*)d_in[11];
    const float* hopwise= (const float*)d_in[12];
    const float* temp   = (const float*)d_in[13];
    float* out = (float*)d_out;

    char* ws = (char*)d_ws;
    size_t off = 0;
    auto alloc = [&](size_t bytes) -> void* {
        void* p = ws + off;
        off += (bytes + 255) & ~(size_t)255;
        return p;
    };
    int*      deg    = (int*)alloc((size_t)kN * 4);
    int*      cursor = (int*)alloc((size_t)kN * 4);
    int*      ptr    = (int*)alloc((size_t)(kN + 1) * 4);
    int*      partial= (int*)alloc((size_t)kNB * 4);
    int*      offs   = (int*)alloc((size_t)kNB * 4);
    int*      csrc   = (int*)alloc((size_t)kET * 4);
    float*    cwgt   = (float*)alloc((size_t)kET * 4);
    float*    Q      = (float*)alloc((size_t)kN * kHID * 4);
    float*    Kt0    = (float*)alloc((size_t)kN * kHID * 4);
    float*    Kt1    = (float*)alloc((size_t)kN * kHID * 4);
    float*    Vg     = (float*)alloc((size_t)kN * kH * kC * 4);
    float*    hidden = (float*)alloc((size_t)kN * kH * kC * 4);
    float*    gammas = (float*)alloc(64);
    uint16_t* M1     = (uint16_t*)alloc((size_t)kN * 640 * 2);
    uint16_t* M2     = (uint16_t*)alloc((size_t)kN * 640 * 2);
    (void)ws_size; (void)in_sizes; (void)n_in; (void)out_size;

    // deg & cursor are adjacent in ws: one memset covers both
    size_t deg_span = (size_t)((char*)cursor - (char*)deg) + (size_t)kN * 4;
    hipMemsetAsync(deg, 0, deg_span, stream);

    deg_kernel<<<(kET + 255) / 256, 256, 0, stream>>>(ei, deg);
    degsum_kernel<<<kNB, 256, 0, stream>>>(deg, partial);
    midscan_kernel<<<1, 128, 0, stream>>>(partial, offs, hopwise, temp, gammas);
    ptrw_kernel<<<kNB, 256, 0, stream>>>(deg, offs, ptr);
    scatter_kernel<<<(kET + 255) / 256, 256, 0, stream>>>(ei, deg, ptr, cursor, csrc, cwgt);
    proj_kernel<<<kN / kBN, 256, 0, stream>>>(feat, W_in, b_in, Wq, bq, Wk, bk, Wv, bv,
                                              hopwise, Q, Kt0, hidden, Vg);
    // hop 0 (rank-1 factors, lane-local K): Kt0,Vg -> M1, Kt1
    hop0_kernel<<<kN / 4, 256, 0, stream>>>(ptr, csrc, cwgt, Kt0, Vg, Q, M1, Kt1, hidden,
                                            gammas + 0);
    // hop 1: M1 -> M2, Kt1 -> Kt0
    hop2_kernel<false><<<kN / 4, 256, 0, stream>>>(ptr, csrc, cwgt, M1, M2, Kt1, Kt0, Q, hidden,
                                                   gammas + 4, W_out, b_out, out);
    // hop 2 (last): M2, Kt0 readout only + fused output GEMM
    hop2_kernel<true><<<kN / 4, 256, 0, stream>>>(ptr, csrc, cwgt, M2, M1, Kt0, Kt1, Q, hidden,
                                                  gammas + 8, W_out, b_out, out);
}

// Round 12
// 172.870 us; speedup vs baseline: 1.6677x; 1.0386x over previous
//
#include <hip/hip_runtime.h>
#include <stdint.h>

// Problem constants (match reference)
#define kN   20000
#define kE   160000
#define kET  (kN + kE)   // edges incl self loops = 180000
#define kF   256
#define kHID 64
#define kH   4
#define kHC  16
#define kC   10
#define kK   3
#define kCST 1e-5f
#define kBN  32          // nodes per proj block (625 blocks)
#define kNB  ((kN + 255) / 256)   // 79 partial-scan blocks

__device__ __forceinline__ uint16_t f2bf(float x) {
    uint32_t u = __float_as_uint(x);
    u += 0x7fffu + ((u >> 16) & 1u);   // round-to-nearest-even
    return (uint16_t)(u >> 16);
}
__device__ __forceinline__ float lo16(uint32_t p) { return __uint_as_float(p << 16); }
__device__ __forceinline__ float hi16(uint32_t p) { return __uint_as_float(p & 0xffff0000u); }
__device__ __forceinline__ uint32_t pack2(float a, float b) {
    return ((uint32_t)f2bf(b) << 16) | (uint32_t)f2bf(a);
}

// ---- degree histogram over col (incl self loops) ----
__global__ void deg_kernel(const int* __restrict__ ei, int* __restrict__ deg) {
    int e = blockIdx.x * blockDim.x + threadIdx.x;
    if (e >= kET) return;
    int c = (e < kE) ? ei[kE + e] : (e - kE);
    atomicAdd(&deg[c], 1);
}

// ---- scan stage 1: per-block (256) sums of deg; block 0 also does gammas ----
__global__ __launch_bounds__(256) void degsum_kernel(
    const int* __restrict__ deg, int* __restrict__ partial,
    const float* __restrict__ hopwise, const float* __restrict__ temp,
    float* __restrict__ gammas) {
    __shared__ int sw[4];
    int t = threadIdx.x;
    int idx = blockIdx.x * 256 + t;
    int v = (idx < kN) ? deg[idx] : 0;
#pragma unroll
    for (int off = 32; off >= 1; off >>= 1) v += __shfl_xor(v, off, 64);
    if ((t & 63) == 0) sw[t >> 6] = v;
    __syncthreads();
    if (t == 0) partial[blockIdx.x] = sw[0] + sw[1] + sw[2] + sw[3];
    if (blockIdx.x == 0 && t == 64) {   // gamma precompute (independent work)
        for (int k = 1; k <= kK; ++k) {
            float mx = -1e30f;
            for (int h = 0; h < kH; ++h) mx = fmaxf(mx, temp[h * (kK + 1) + k]);
            float ex[kH]; float sum = 0.f;
            for (int h = 0; h < kH; ++h) { ex[h] = __expf(temp[h * (kK + 1) + k] - mx); sum += ex[h]; }
            for (int h = 0; h < kH; ++h) gammas[(k - 1) * kH + h] = hopwise[k] * ex[h] / sum;
        }
    }
}

// ---- stage 2 (fused): each block reduces partials < blockIdx for its offset,
//      then writes ptr[idx] = offset + in-block exclusive prefix ----
__global__ __launch_bounds__(256) void ptrw_kernel(const int* __restrict__ deg,
                                                   const int* __restrict__ partial,
                                                   int* __restrict__ ptr) {
    __shared__ int red[4];
    __shared__ int boffs;
    int t = threadIdx.x;
    // block offset = sum of partial[j], j < blockIdx.x  (kNB = 79 < 256)
    int pv = (t < kNB && t < blockIdx.x) ? partial[t] : 0;
#pragma unroll
    for (int off = 32; off >= 1; off >>= 1) pv += __shfl_xor(pv, off, 64);
    if ((t & 63) == 0) red[t >> 6] = pv;
    __syncthreads();
    if (t == 0) boffs = red[0] + red[1] + red[2] + red[3];
    __syncthreads();   // boffs ready; red free for reuse
    int idx = blockIdx.x * 256 + t;
    int v = (idx < kN) ? deg[idx] : 0;
    int incl = v;
#pragma unroll
    for (int off = 1; off < 64; off <<= 1) {
        int u = __shfl_up(incl, off, 64);
        if ((t & 63) >= off) incl += u;
    }
    int wid = t >> 6;
    if ((t & 63) == 63) red[wid] = incl;
    __syncthreads();
    int wadd = 0;
    for (int j = 0; j < 4; ++j) wadd += (j < wid) ? red[j] : 0;
    int excl = boffs + wadd + incl - v;
    if (idx < kN) ptr[idx] = excl;
    if (idx == kN - 1) ptr[kN] = excl + v;
}

// ---- CSR (by col) build: scatter (row, norm); norm from deg via rsqrt ----
__global__ void scatter_kernel(const int* __restrict__ ei, const int* __restrict__ deg,
                               const int* __restrict__ ptr, int* __restrict__ cursor,
                               int* __restrict__ src, float* __restrict__ wgt) {
    int e = blockIdx.x * blockDim.x + threadIdx.x;
    if (e >= kET) return;
    int r, c;
    if (e < kE) { r = ei[e]; c = ei[kE + e]; } else { r = c = e - kE; }
    float wv = rsqrtf((float)deg[r]) * rsqrtf((float)deg[c]);
    int pos = ptr[c] + atomicAdd(&cursor[c], 1);
    src[pos] = r;
    wgt[pos] = wv;
}

// ---- fused projections, 32 nodes/block x 625 blocks (r9-proven). ----
__global__ __launch_bounds__(256) void proj_kernel(
    const float* __restrict__ feat, const float* __restrict__ W_in, const float* __restrict__ b_in,
    const float* __restrict__ Wq, const float* __restrict__ bq,
    const float* __restrict__ Wk, const float* __restrict__ bk,
    const float* __restrict__ Wv, const float* __restrict__ bv,
    const float* __restrict__ hopwise,
    float* __restrict__ Qg, float* __restrict__ Ktg, float* __restrict__ hidden,
    float* __restrict__ Vg) {
    __shared__ float sF[kBN * 68];   // feat k-tile
    __shared__ float sW[64 * 68];    // W_in tile -> Wq -> Wk -> Wv
    __shared__ float sX[kBN * 68];   // x

    int t = threadIdx.x;
    int tx = t & 15, ty = t >> 4;    // 16 x 16 thread grid
    int n0 = blockIdx.x * kBN;
    int r0 = ty * 2, r1 = ty * 2 + 1;

    float acc[2][4];
#pragma unroll
    for (int i = 0; i < 2; ++i)
#pragma unroll
        for (int j = 0; j < 4; ++j) acc[i][j] = 0.f;

    for (int ks = 0; ks < 4; ++ks) {
        int k0 = ks * 64;
#pragma unroll
        for (int i = 0; i < 2; ++i) {
            int slot = t + 256 * i;
            int row = slot >> 4, cg = slot & 15;
            *(float4*)&sF[row * 68 + cg * 4] =
                *(const float4*)&feat[(size_t)(n0 + row) * kF + k0 + cg * 4];
        }
#pragma unroll
        for (int i = 0; i < 4; ++i) {
            int slot = t + 256 * i;
            int row = slot >> 4, cg = slot & 15;
            *(float4*)&sW[row * 68 + cg * 4] =
                *(const float4*)&W_in[(size_t)(k0 + row) * kHID + cg * 4];
        }
        __syncthreads();
#pragma unroll 8
        for (int kk = 0; kk < 64; ++kk) {
            float4 b = *(float4*)&sW[kk * 68 + tx * 4];
            float a0 = sF[r0 * 68 + kk], a1 = sF[r1 * 68 + kk];
            acc[0][0] += a0 * b.x; acc[0][1] += a0 * b.y;
            acc[0][2] += a0 * b.z; acc[0][3] += a0 * b.w;
            acc[1][0] += a1 * b.x; acc[1][1] += a1 * b.y;
            acc[1][2] += a1 * b.z; acc[1][3] += a1 * b.w;
        }
        __syncthreads();
    }
    {
        float bb[4];
#pragma unroll
        for (int j = 0; j < 4; ++j) bb[j] = b_in[tx * 4 + j];
#pragma unroll
        for (int i = 0; i < 2; ++i) {
            float4 xr;
            xr.x = fmaxf(acc[i][0] + bb[0], 0.f);
            xr.y = fmaxf(acc[i][1] + bb[1], 0.f);
            xr.z = fmaxf(acc[i][2] + bb[2], 0.f);
            xr.w = fmaxf(acc[i][3] + bb[3], 0.f);
            *(float4*)&sX[(r0 + i) * 68 + tx * 4] = xr;
        }
    }
#pragma unroll
    for (int i = 0; i < 4; ++i) {
        int slot = t + 256 * i;
        int row = slot >> 4, cg = slot & 15;
        *(float4*)&sW[row * 68 + cg * 4] = *(const float4*)&Wq[(size_t)row * kHID + cg * 4];
    }
    __syncthreads();

    float qa[2][4];
#pragma unroll
    for (int i = 0; i < 2; ++i)
#pragma unroll
        for (int j = 0; j < 4; ++j) qa[i][j] = 0.f;
#pragma unroll 8
    for (int kk = 0; kk < 64; ++kk) {
        float4 b = *(float4*)&sW[kk * 68 + tx * 4];
        float a0 = sX[r0 * 68 + kk], a1 = sX[r1 * 68 + kk];
        qa[0][0] += a0 * b.x; qa[0][1] += a0 * b.y;
        qa[0][2] += a0 * b.z; qa[0][3] += a0 * b.w;
        qa[1][0] += a1 * b.x; qa[1][1] += a1 * b.y;
        qa[1][2] += a1 * b.z; qa[1][3] += a1 * b.w;
    }
    {
        float bqv[4];
#pragma unroll
        for (int j = 0; j < 4; ++j) bqv[j] = bq[tx * 4 + j];
#pragma unroll
        for (int i = 0; i < 2; ++i) {
            float4 qv;
            float q0 = qa[i][0] + bqv[0], q1 = qa[i][1] + bqv[1];
            float q2 = qa[i][2] + bqv[2], q3 = qa[i][3] + bqv[3];
            qv.x = (q0 > 0.f) ? 1.f + q0 : __expf(q0);
            qv.y = (q1 > 0.f) ? 1.f + q1 : __expf(q1);
            qv.z = (q2 > 0.f) ? 1.f + q2 : __expf(q2);
            qv.w = (q3 > 0.f) ? 1.f + q3 : __expf(q3);
            *(float4*)&Qg[(size_t)(n0 + r0 + i) * kHID + tx * 4] = qv;
        }
    }
    __syncthreads();
#pragma unroll
    for (int i = 0; i < 4; ++i) {
        int slot = t + 256 * i;
        int row = slot >> 4, cg = slot & 15;
        *(float4*)&sW[row * 68 + cg * 4] = *(const float4*)&Wk[(size_t)row * kHID + cg * 4];
    }
    __syncthreads();

    float ka[2][4];
#pragma unroll
    for (int i = 0; i < 2; ++i)
#pragma unroll
        for (int j = 0; j < 4; ++j) ka[i][j] = 0.f;
#pragma unroll 8
    for (int kk = 0; kk < 64; ++kk) {
        float4 b = *(float4*)&sW[kk * 68 + tx * 4];
        float a0 = sX[r0 * 68 + kk], a1 = sX[r1 * 68 + kk];
        ka[0][0] += a0 * b.x; ka[0][1] += a0 * b.y;
        ka[0][2] += a0 * b.z; ka[0][3] += a0 * b.w;
        ka[1][0] += a1 * b.x; ka[1][1] += a1 * b.y;
        ka[1][2] += a1 * b.z; ka[1][3] += a1 * b.w;
    }
    {
        float bkv[4];
#pragma unroll
        for (int j = 0; j < 4; ++j) bkv[j] = bk[tx * 4 + j];
#pragma unroll
        for (int i = 0; i < 2; ++i) {
            float4 kv;
            float k0v = ka[i][0] + bkv[0], k1v = ka[i][1] + bkv[1];
            float k2v = ka[i][2] + bkv[2], k3v = ka[i][3] + bkv[3];
            kv.x = (k0v > 0.f) ? 1.f + k0v : __expf(k0v);
            kv.y = (k1v > 0.f) ? 1.f + k1v : __expf(k1v);
            kv.z = (k2v > 0.f) ? 1.f + k2v : __expf(k2v);
            kv.w = (k3v > 0.f) ? 1.f + k3v : __expf(k3v);
            *(float4*)&Ktg[(size_t)(n0 + r0 + i) * kHID + tx * 4] = kv;
        }
    }
    __syncthreads();
#pragma unroll
    for (int i = 0; i < 3; ++i) {
        int slot = t + 256 * i;
        if (slot < 640) {
            int row = slot / 10, cg = slot % 10;
            *(float4*)&sW[row * 44 + cg * 4] = *(const float4*)&Wv[(size_t)row * 40 + cg * 4];
        }
    }
    __syncthreads();

    if (t < 160) {
        int txv = t % 10, tyv = t / 10;
        int vr0 = tyv * 2;
        float va[2][4];
#pragma unroll
        for (int i = 0; i < 2; ++i)
#pragma unroll
            for (int j = 0; j < 4; ++j) va[i][j] = 0.f;
#pragma unroll 8
        for (int kk = 0; kk < 64; ++kk) {
            float4 b = *(float4*)&sW[kk * 44 + txv * 4];
            float a0 = sX[vr0 * 68 + kk], a1 = sX[(vr0 + 1) * 68 + kk];
            va[0][0] += a0 * b.x; va[0][1] += a0 * b.y;
            va[0][2] += a0 * b.z; va[0][3] += a0 * b.w;
            va[1][0] += a1 * b.x; va[1][1] += a1 * b.y;
            va[1][2] += a1 * b.z; va[1][3] += a1 * b.w;
        }
        float bvv[4];
#pragma unroll
        for (int j = 0; j < 4; ++j) bvv[j] = bv[txv * 4 + j];
        float hw0 = hopwise[0];
#pragma unroll
        for (int i = 0; i < 2; ++i) {
            int row = vr0 + i;
            float4 vr;
            vr.x = va[i][0] + bvv[0]; vr.y = va[i][1] + bvv[1];
            vr.z = va[i][2] + bvv[2]; vr.w = va[i][3] + bvv[3];
            *(float4*)&Vg[(size_t)(n0 + row) * 40 + txv * 4] = vr;
            float4 hr;
            hr.x = vr.x * hw0; hr.y = vr.y * hw0; hr.z = vr.z * hw0; hr.w = vr.w * hw0;
            *(float4*)&hidden[(size_t)(n0 + row) * 40 + txv * 4] = hr;
        }
    }
}

// ---- hop 0, rank-1, lane-local K + DIRECT V loads (no DS ops):
//      lane l owns canonical values [10l,10l+10): K factor = Kt[s][l] (own
//      load); V span = V[s][10*(l>>4) .. +10) loaded as 5x float2 (8B-aligned,
//      16 lanes/group hit identical lines -> broadcast coalesce).
__global__ __launch_bounds__(256) void hop0_kernel(
    const int* __restrict__ ptr, const int* __restrict__ src, const float* __restrict__ wgt,
    const float* __restrict__ Ktin, const float* __restrict__ Vin,
    const float* __restrict__ Q,
    uint16_t* __restrict__ Mout, float* __restrict__ Ktout,
    float* __restrict__ hidden, const float* __restrict__ gammas) {
    __shared__ float Ml[4][640];
    __shared__ float Ktl[4][64];
    __shared__ float Ql[4][64];
    int w = threadIdx.x >> 6;
    int l = threadIdx.x & 63;
    int n = blockIdx.x * 4 + w;
    int beg = ptr[n], end = ptr[n + 1];

    Ql[w][l] = Q[(size_t)n * 64 + l];

    int base_v = 10 * (l >> 4);

    float m[10];
#pragma unroll
    for (int i = 0; i < 10; ++i) m[i] = 0.f;
    float kacc = 0.f;

    auto edge = [&](int su, float wv) {
        float kl = Ktin[(size_t)su * 64 + l];
        const float* vr = Vin + (size_t)su * 40 + base_v;
        float2 v0 = *(const float2*)vr;
        float2 v1 = *(const float2*)(vr + 2);
        float2 v2 = *(const float2*)(vr + 4);
        float2 v3 = *(const float2*)(vr + 6);
        float2 v4 = *(const float2*)(vr + 8);
        float kw = wv * kl;
        kacc += wv * kl;
        m[0] += kw * v0.x; m[1] += kw * v0.y;
        m[2] += kw * v1.x; m[3] += kw * v1.y;
        m[4] += kw * v2.x; m[5] += kw * v2.y;
        m[6] += kw * v3.x; m[7] += kw * v3.y;
        m[8] += kw * v4.x; m[9] += kw * v4.y;
    };

    int e = beg;
    for (; e + 4 <= end; e += 4) {
        int s0 = src[e], s1 = src[e + 1], s2 = src[e + 2], s3 = src[e + 3];
        float w0 = wgt[e], w1 = wgt[e + 1], w2 = wgt[e + 2], w3 = wgt[e + 3];
        edge(s0, w0); edge(s1, w1); edge(s2, w2); edge(s3, w3);
    }
    for (; e < end; ++e) edge(src[e], wgt[e]);

    // write M1 (canonical words 5l..5l+4) + Kt1
    {
        uint32_t* orow = (uint32_t*)Mout + (size_t)n * 320 + 5 * l;
        orow[0] = pack2(m[0], m[1]);
        orow[1] = pack2(m[2], m[3]);
        orow[2] = pack2(m[4], m[5]);
        orow[3] = pack2(m[6], m[7]);
        orow[4] = pack2(m[8], m[9]);
        Ktout[(size_t)n * 64 + l] = kacc;
    }
#pragma unroll
    for (int c = 0; c < 10; c += 2)
        *(float2*)&Ml[w][10 * l + c] = make_float2(m[c], m[c + 1]);
    Ktl[w][l] = kacc;
    __syncthreads();

    int tt = threadIdx.x;
    if (tt < 160) {
        int ww = tt / 40, o = tt % 40;
        int h = o / 10, j = o % 10;
        const float* q  = &Ql[ww][h * 16];
        const float* kk = &Ktl[ww][h * 16];
        const float* mm = &Ml[ww][h * 160 + j];
        float cd = kCST, hh = 0.f;
#pragma unroll
        for (int i = 0; i < 16; ++i) { cd += q[i] * kk[i]; hh += q[i] * mm[i * 10]; }
        int nn = blockIdx.x * 4 + ww;
        hidden[(size_t)nn * 40 + o] += gammas[h] * hh / cd;
    }
}

// ---- hops 1-2, wave-per-node (r9-exact, proven 44.4 us / 126 MB): gather M
//      (bf16, 5 dwords/lane, plane layout) & Kt, 4-edge unroll; Hh/Cd epilogue.
//      LAST: skip M/Kt writeback, fuse output GEMM.
template<bool LAST>
__global__ __launch_bounds__(256) void hop2_kernel(
    const int* __restrict__ ptr, const int* __restrict__ src, const float* __restrict__ wgt,
    const uint16_t* __restrict__ Min, uint16_t* __restrict__ Mout,
    const float* __restrict__ Ktin, float* __restrict__ Ktout,
    const float* __restrict__ Q, float* __restrict__ hidden,
    const float* __restrict__ gammas,
    const float* __restrict__ W_out, const float* __restrict__ b_out,
    float* __restrict__ out) {
    __shared__ float Ml[4][640];
    __shared__ float Ktl[4][64];
    __shared__ float Ql[4][64];
    __shared__ float Hl[4][40];
    int w = threadIdx.x >> 6;     // node slot
    int l = threadIdx.x & 63;     // lane
    int n = blockIdx.x * 4 + w;
    int beg = ptr[n], end = ptr[n + 1];
    const uint32_t* Mw = (const uint32_t*)Min;

    Ql[w][l] = Q[(size_t)n * 64 + l];   // hoisted: overlaps with gather

    float m0=0,m1=0,m2=0,m3=0,m4=0,m5=0,m6=0,m7=0,m8=0,m9=0;
    float kacc = 0.f;
    int e = beg;
    for (; e + 4 <= end; e += 4) {
        int s0 = src[e], s1 = src[e + 1], s2 = src[e + 2], s3 = src[e + 3];
        float w0 = wgt[e], w1 = wgt[e + 1], w2 = wgt[e + 2], w3 = wgt[e + 3];
        const uint32_t* p0 = Mw + (size_t)s0 * 320 + l;
        const uint32_t* p1 = Mw + (size_t)s1 * 320 + l;
        const uint32_t* p2 = Mw + (size_t)s2 * 320 + l;
        const uint32_t* p3 = Mw + (size_t)s3 * 320 + l;
        uint32_t a0 = p0[0], a1 = p0[64], a2 = p0[128], a3 = p0[192], a4 = p0[256];
        uint32_t b0 = p1[0], b1 = p1[64], b2 = p1[128], b3 = p1[192], b4 = p1[256];
        uint32_t c0 = p2[0], c1 = p2[64], c2 = p2[128], c3 = p2[192], c4 = p2[256];
        uint32_t d0 = p3[0], d1 = p3[64], d2 = p3[128], d3 = p3[192], d4 = p3[256];
        float ka = Ktin[(size_t)s0 * 64 + l], kb = Ktin[(size_t)s1 * 64 + l];
        float kc = Ktin[(size_t)s2 * 64 + l], kd = Ktin[(size_t)s3 * 64 + l];
        m0 += w0 * lo16(a0); m1 += w0 * hi16(a0);
        m2 += w0 * lo16(a1); m3 += w0 * hi16(a1);
        m4 += w0 * lo16(a2); m5 += w0 * hi16(a2);
        m6 += w0 * lo16(a3); m7 += w0 * hi16(a3);
        m8 += w0 * lo16(a4); m9 += w0 * hi16(a4);
        m0 += w1 * lo16(b0); m1 += w1 * hi16(b0);
        m2 += w1 * lo16(b1); m3 += w1 * hi16(b1);
        m4 += w1 * lo16(b2); m5 += w1 * hi16(b2);
        m6 += w1 * lo16(b3); m7 += w1 * hi16(b3);
        m8 += w1 * lo16(b4); m9 += w1 * hi16(b4);
        m0 += w2 * lo16(c0); m1 += w2 * hi16(c0);
        m2 += w2 * lo16(c1); m3 += w2 * hi16(c1);
        m4 += w2 * lo16(c2); m5 += w2 * hi16(c2);
        m6 += w2 * lo16(c3); m7 += w2 * hi16(c3);
        m8 += w2 * lo16(c4); m9 += w2 * hi16(c4);
        m0 += w3 * lo16(d0); m1 += w3 * hi16(d0);
        m2 += w3 * lo16(d1); m3 += w3 * hi16(d1);
        m4 += w3 * lo16(d2); m5 += w3 * hi16(d2);
        m6 += w3 * lo16(d3); m7 += w3 * hi16(d3);
        m8 += w3 * lo16(d4); m9 += w3 * hi16(d4);
        kacc += w0 * ka + w1 * kb + w2 * kc + w3 * kd;
    }
    for (; e + 2 <= end; e += 2) {
        int s0 = src[e], s1 = src[e + 1];
        float w0 = wgt[e], w1 = wgt[e + 1];
        const uint32_t* p0 = Mw + (size_t)s0 * 320 + l;
        const uint32_t* p1 = Mw + (size_t)s1 * 320 + l;
        uint32_t a0 = p0[0], a1 = p0[64], a2 = p0[128], a3 = p0[192], a4 = p0[256];
        uint32_t b0 = p1[0], b1 = p1[64], b2 = p1[128], b3 = p1[192], b4 = p1[256];
        float ka = Ktin[(size_t)s0 * 64 + l], kb = Ktin[(size_t)s1 * 64 + l];
        m0 += w0 * lo16(a0); m1 += w0 * hi16(a0);
        m2 += w0 * lo16(a1); m3 += w0 * hi16(a1);
        m4 += w0 * lo16(a2); m5 += w0 * hi16(a2);
        m6 += w0 * lo16(a3); m7 += w0 * hi16(a3);
        m8 += w0 * lo16(a4); m9 += w0 * hi16(a4);
        m0 += w1 * lo16(b0); m1 += w1 * hi16(b0);
        m2 += w1 * lo16(b1); m3 += w1 * hi16(b1);
        m4 += w1 * lo16(b2); m5 += w1 * hi16(b2);
        m6 += w1 * lo16(b3); m7 += w1 * hi16(b3);
        m8 += w1 * lo16(b4); m9 += w1 * hi16(b4);
        kacc += w0 * ka + w1 * kb;
    }
    if (e < end) {
        int s0 = src[e];
        float w0 = wgt[e];
        const uint32_t* p0 = Mw + (size_t)s0 * 320 + l;
        uint32_t a0 = p0[0], a1 = p0[64], a2 = p0[128], a3 = p0[192], a4 = p0[256];
        float ka = Ktin[(size_t)s0 * 64 + l];
        m0 += w0 * lo16(a0); m1 += w0 * hi16(a0);
        m2 += w0 * lo16(a1); m3 += w0 * hi16(a1);
        m4 += w0 * lo16(a2); m5 += w0 * hi16(a2);
        m6 += w0 * lo16(a3); m7 += w0 * hi16(a3);
        m8 += w0 * lo16(a4); m9 += w0 * hi16(a4);
        kacc += w0 * ka;
    }

    // stage to LDS (word (l+64c) holds values 2(l+64c), 2(l+64c)+1)
    *(float2*)&Ml[w][2 * l]         = make_float2(m0, m1);
    *(float2*)&Ml[w][2 * (l + 64)]  = make_float2(m2, m3);
    *(float2*)&Ml[w][2 * (l + 128)] = make_float2(m4, m5);
    *(float2*)&Ml[w][2 * (l + 192)] = make_float2(m6, m7);
    *(float2*)&Ml[w][2 * (l + 256)] = make_float2(m8, m9);
    Ktl[w][l] = kacc;
    if constexpr (!LAST) {
        uint32_t* orow = (uint32_t*)Mout + (size_t)n * 320 + l;
        orow[0]   = pack2(m0, m1);
        orow[64]  = pack2(m2, m3);
        orow[128] = pack2(m4, m5);
        orow[192] = pack2(m6, m7);
        orow[256] = pack2(m8, m9);
        Ktout[(size_t)n * 64 + l] = kacc;
    }
    __syncthreads();

    int tt = threadIdx.x;
    if (tt < 160) {
        int ww = tt / 40, o = tt % 40;
        int h = o / 10, j = o % 10;
        const float* q  = &Ql[ww][h * 16];
        const float* kk = &Ktl[ww][h * 16];
        const float* mm = &Ml[ww][h * 160 + j];
        float cd = kCST, hh = 0.f;
#pragma unroll
        for (int i = 0; i < 16; ++i) { cd += q[i] * kk[i]; hh += q[i] * mm[i * 10]; }
        int nn = blockIdx.x * 4 + ww;
        float val = hidden[(size_t)nn * 40 + o] + gammas[h] * hh / cd;
        if constexpr (!LAST) hidden[(size_t)nn * 40 + o] = val;
        else Hl[ww][o] = val;
    }
    if constexpr (LAST) {
        __syncthreads();
        if (tt < 40) {
            int ww = tt / 10, c = tt % 10;
            float acc = b_out[c];
#pragma unroll
            for (int i = 0; i < 40; ++i) acc += Hl[ww][i] * W_out[i * 10 + c];
            out[(size_t)(blockIdx.x * 4 + ww) * 10 + c] = acc;
        }
    }
}

extern "C" void kernel_launch(void* const* d_in, const int* in_sizes, int n_in,
                              void* d_out, int out_size, void* d_ws, size_t ws_size,
                              hipStream_t stream) {
    const float* feat   = (const float*)d_in[0];
    const int*   ei     = (const int*)d_in[1];
    const float* W_in   = (const float*)d_in[2];
    const float* b_in   = (const float*)d_in[3];
    const float* Wq     = (const float*)d_in[4];
    const float* bq     = (const float*)d_in[5];
    const float* Wk     = (const float*)d_in[6];
    const float* bk     = (const float*)d_in[7];
    const float* Wv     = (const float*)d_in[8];
    const float* bv     = (const float*)d_in[9];
    const float* W_out  = (const float*)d_in[10];
    const float* b_out  = (const float*)d_in[11];
    const float* hopwise= (const float*)d_in[12];
    const float* temp   = (const float*)d_in[13];
    float* out = (float*)d_out;

    char* ws = (char*)d_ws;
    size_t off = 0;
    auto alloc = [&](size_t bytes) -> void* {
        void* p = ws + off;
        off += (bytes + 255) & ~(size_t)255;
        return p;
    };
    int*      deg    = (int*)alloc((size_t)kN * 4);
    int*      cursor = (int*)alloc((size_t)kN * 4);
    int*      ptr    = (int*)alloc((size_t)(kN + 1) * 4);
    int*      partial= (int*)alloc((size_t)kNB * 4);
    int*      csrc   = (int*)alloc((size_t)kET * 4);
    float*    cwgt   = (float*)alloc((size_t)kET * 4);
    float*    Q      = (float*)alloc((size_t)kN * kHID * 4);
    float*    Kt0    = (float*)alloc((size_t)kN * kHID * 4);
    float*    Kt1    = (float*)alloc((size_t)kN * kHID * 4);
    float*    Vg     = (float*)alloc((size_t)kN * kH * kC * 4);
    float*    hidden = (float*)alloc((size_t)kN * kH * kC * 4);
    float*    gammas = (float*)alloc(64);
    uint16_t* M1     = (uint16_t*)alloc((size_t)kN * 640 * 2);
    uint16_t* M2     = (uint16_t*)alloc((size_t)kN * 640 * 2);
    (void)ws_size; (void)in_sizes; (void)n_in; (void)out_size;

    // deg & cursor are adjacent in ws: one memset covers both
    size_t deg_span = (size_t)((char*)cursor - (char*)deg) + (size_t)kN * 4;
    hipMemsetAsync(deg, 0, deg_span, stream);

    deg_kernel<<<(kET + 255) / 256, 256, 0, stream>>>(ei, deg);
    degsum_kernel<<<kNB, 256, 0, stream>>>(deg, partial, hopwise, temp, gammas);
    ptrw_kernel<<<kNB, 256, 0, stream>>>(deg, partial, ptr);
    scatter_kernel<<<(kET + 255) / 256, 256, 0, stream>>>(ei, deg, ptr, cursor, csrc, cwgt);
    proj_kernel<<<kN / kBN, 256, 0, stream>>>(feat, W_in, b_in, Wq, bq, Wk, bk, Wv, bv,
                                              hopwise, Q, Kt0, hidden, Vg);
    // hop 0 (rank-1 factors, lane-local K + direct V loads): Kt0,Vg -> M1, Kt1
    hop0_kernel<<<kN / 4, 256, 0, stream>>>(ptr, csrc, cwgt, Kt0, Vg, Q, M1, Kt1, hidden,
                                            gammas + 0);
    // hop 1: M1 -> M2, Kt1 -> Kt0
    hop2_kernel<false><<<kN / 4, 256, 0, stream>>>(ptr, csrc, cwgt, M1, M2, Kt1, Kt0, Q, hidden,
                                                   gammas + 4, W_out, b_out, out);
    // hop 2 (last): M2, Kt0 readout only + fused output GEMM
    hop2_kernel<true><<<kN / 4, 256, 0, stream>>>(ptr, csrc, cwgt, M2, M1, Kt0, Kt1, Q, hidden,
                                                  gammas + 8, W_out, b_out, out);
}

// Round 13
// 166.048 us; speedup vs baseline: 1.7362x; 1.0411x over previous
//
#include <hip/hip_runtime.h>
#include <stdint.h>

// Problem constants (match reference)
#define kN   20000
#define kE   160000
#define kET  (kN + kE)   // edges incl self loops = 180000
#define kF   256
#define kHID 64
#define kH   4
#define kHC  16
#define kC   10
#define kK   3
#define kCST 1e-5f
#define kBN  32          // nodes per proj block (625 blocks)
#define kNB  ((kN + 255) / 256)   // 79 partial-scan blocks

__device__ __forceinline__ uint16_t f2bf(float x) {
    uint32_t u = __float_as_uint(x);
    u += 0x7fffu + ((u >> 16) & 1u);   // round-to-nearest-even
    return (uint16_t)(u >> 16);
}
__device__ __forceinline__ float bf2f(uint16_t h) {
    return __uint_as_float(((uint32_t)h) << 16);
}
__device__ __forceinline__ float lo16(uint32_t p) { return __uint_as_float(p << 16); }
__device__ __forceinline__ float hi16(uint32_t p) { return __uint_as_float(p & 0xffff0000u); }
__device__ __forceinline__ uint32_t pack2(float a, float b) {
    return ((uint32_t)f2bf(b) << 16) | (uint32_t)f2bf(a);
}

// ---- degree histogram over col (incl self loops) ----
__global__ void deg_kernel(const int* __restrict__ ei, int* __restrict__ deg) {
    int e = blockIdx.x * blockDim.x + threadIdx.x;
    if (e >= kET) return;
    int c = (e < kE) ? ei[kE + e] : (e - kE);
    atomicAdd(&deg[c], 1);
}

// ---- scan stage 1: per-block (256) sums of deg; block 0 also does gammas ----
__global__ __launch_bounds__(256) void degsum_kernel(
    const int* __restrict__ deg, int* __restrict__ partial,
    const float* __restrict__ hopwise, const float* __restrict__ temp,
    float* __restrict__ gammas) {
    __shared__ int sw[4];
    int t = threadIdx.x;
    int idx = blockIdx.x * 256 + t;
    int v = (idx < kN) ? deg[idx] : 0;
#pragma unroll
    for (int off = 32; off >= 1; off >>= 1) v += __shfl_xor(v, off, 64);
    if ((t & 63) == 0) sw[t >> 6] = v;
    __syncthreads();
    if (t == 0) partial[blockIdx.x] = sw[0] + sw[1] + sw[2] + sw[3];
    if (blockIdx.x == 0 && t == 64) {   // gamma precompute (independent work)
        for (int k = 1; k <= kK; ++k) {
            float mx = -1e30f;
            for (int h = 0; h < kH; ++h) mx = fmaxf(mx, temp[h * (kK + 1) + k]);
            float ex[kH]; float sum = 0.f;
            for (int h = 0; h < kH; ++h) { ex[h] = __expf(temp[h * (kK + 1) + k] - mx); sum += ex[h]; }
            for (int h = 0; h < kH; ++h) gammas[(k - 1) * kH + h] = hopwise[k] * ex[h] / sum;
        }
    }
}

// ---- stage 2 (fused): each block reduces partials < blockIdx for its offset,
//      then writes ptr[idx] = offset + in-block exclusive prefix ----
__global__ __launch_bounds__(256) void ptrw_kernel(const int* __restrict__ deg,
                                                   const int* __restrict__ partial,
                                                   int* __restrict__ ptr) {
    __shared__ int red[4];
    __shared__ int boffs;
    int t = threadIdx.x;
    int pv = (t < kNB && t < blockIdx.x) ? partial[t] : 0;
#pragma unroll
    for (int off = 32; off >= 1; off >>= 1) pv += __shfl_xor(pv, off, 64);
    if ((t & 63) == 0) red[t >> 6] = pv;
    __syncthreads();
    if (t == 0) boffs = red[0] + red[1] + red[2] + red[3];
    __syncthreads();   // boffs ready; red free for reuse
    int idx = blockIdx.x * 256 + t;
    int v = (idx < kN) ? deg[idx] : 0;
    int incl = v;
#pragma unroll
    for (int off = 1; off < 64; off <<= 1) {
        int u = __shfl_up(incl, off, 64);
        if ((t & 63) >= off) incl += u;
    }
    int wid = t >> 6;
    if ((t & 63) == 63) red[wid] = incl;
    __syncthreads();
    int wadd = 0;
    for (int j = 0; j < 4; ++j) wadd += (j < wid) ? red[j] : 0;
    int excl = boffs + wadd + incl - v;
    if (idx < kN) ptr[idx] = excl;
    if (idx == kN - 1) ptr[kN] = excl + v;
}

// ---- CSR (by col) build: scatter (row, norm); norm from deg via rsqrt ----
__global__ void scatter_kernel(const int* __restrict__ ei, const int* __restrict__ deg,
                               const int* __restrict__ ptr, int* __restrict__ cursor,
                               int* __restrict__ src, float* __restrict__ wgt) {
    int e = blockIdx.x * blockDim.x + threadIdx.x;
    if (e >= kET) return;
    int r, c;
    if (e < kE) { r = ei[e]; c = ei[kE + e]; } else { r = c = e - kE; }
    float wv = rsqrtf((float)deg[r]) * rsqrtf((float)deg[c]);
    int pos = ptr[c] + atomicAdd(&cursor[c], 1);
    src[pos] = r;
    wgt[pos] = wv;
}

// ---- fused projections, 32 nodes/block x 625 blocks (r9-proven). ----
__global__ __launch_bounds__(256) void proj_kernel(
    const float* __restrict__ feat, const float* __restrict__ W_in, const float* __restrict__ b_in,
    const float* __restrict__ Wq, const float* __restrict__ bq,
    const float* __restrict__ Wk, const float* __restrict__ bk,
    const float* __restrict__ Wv, const float* __restrict__ bv,
    const float* __restrict__ hopwise,
    float* __restrict__ Qg, float* __restrict__ Ktg, float* __restrict__ hidden,
    float* __restrict__ Vg) {
    __shared__ float sF[kBN * 68];   // feat k-tile
    __shared__ float sW[64 * 68];    // W_in tile -> Wq -> Wk -> Wv
    __shared__ float sX[kBN * 68];   // x

    int t = threadIdx.x;
    int tx = t & 15, ty = t >> 4;    // 16 x 16 thread grid
    int n0 = blockIdx.x * kBN;
    int r0 = ty * 2, r1 = ty * 2 + 1;

    float acc[2][4];
#pragma unroll
    for (int i = 0; i < 2; ++i)
#pragma unroll
        for (int j = 0; j < 4; ++j) acc[i][j] = 0.f;

    for (int ks = 0; ks < 4; ++ks) {
        int k0 = ks * 64;
#pragma unroll
        for (int i = 0; i < 2; ++i) {
            int slot = t + 256 * i;
            int row = slot >> 4, cg = slot & 15;
            *(float4*)&sF[row * 68 + cg * 4] =
                *(const float4*)&feat[(size_t)(n0 + row) * kF + k0 + cg * 4];
        }
#pragma unroll
        for (int i = 0; i < 4; ++i) {
            int slot = t + 256 * i;
            int row = slot >> 4, cg = slot & 15;
            *(float4*)&sW[row * 68 + cg * 4] =
                *(const float4*)&W_in[(size_t)(k0 + row) * kHID + cg * 4];
        }
        __syncthreads();
#pragma unroll 8
        for (int kk = 0; kk < 64; ++kk) {
            float4 b = *(float4*)&sW[kk * 68 + tx * 4];
            float a0 = sF[r0 * 68 + kk], a1 = sF[r1 * 68 + kk];
            acc[0][0] += a0 * b.x; acc[0][1] += a0 * b.y;
            acc[0][2] += a0 * b.z; acc[0][3] += a0 * b.w;
            acc[1][0] += a1 * b.x; acc[1][1] += a1 * b.y;
            acc[1][2] += a1 * b.z; acc[1][3] += a1 * b.w;
        }
        __syncthreads();
    }
    {
        float bb[4];
#pragma unroll
        for (int j = 0; j < 4; ++j) bb[j] = b_in[tx * 4 + j];
#pragma unroll
        for (int i = 0; i < 2; ++i) {
            float4 xr;
            xr.x = fmaxf(acc[i][0] + bb[0], 0.f);
            xr.y = fmaxf(acc[i][1] + bb[1], 0.f);
            xr.z = fmaxf(acc[i][2] + bb[2], 0.f);
            xr.w = fmaxf(acc[i][3] + bb[3], 0.f);
            *(float4*)&sX[(r0 + i) * 68 + tx * 4] = xr;
        }
    }
#pragma unroll
    for (int i = 0; i < 4; ++i) {
        int slot = t + 256 * i;
        int row = slot >> 4, cg = slot & 15;
        *(float4*)&sW[row * 68 + cg * 4] = *(const float4*)&Wq[(size_t)row * kHID + cg * 4];
    }
    __syncthreads();

    float qa[2][4];
#pragma unroll
    for (int i = 0; i < 2; ++i)
#pragma unroll
        for (int j = 0; j < 4; ++j) qa[i][j] = 0.f;
#pragma unroll 8
    for (int kk = 0; kk < 64; ++kk) {
        float4 b = *(float4*)&sW[kk * 68 + tx * 4];
        float a0 = sX[r0 * 68 + kk], a1 = sX[r1 * 68 + kk];
        qa[0][0] += a0 * b.x; qa[0][1] += a0 * b.y;
        qa[0][2] += a0 * b.z; qa[0][3] += a0 * b.w;
        qa[1][0] += a1 * b.x; qa[1][1] += a1 * b.y;
        qa[1][2] += a1 * b.z; qa[1][3] += a1 * b.w;
    }
    {
        float bqv[4];
#pragma unroll
        for (int j = 0; j < 4; ++j) bqv[j] = bq[tx * 4 + j];
#pragma unroll
        for (int i = 0; i < 2; ++i) {
            float4 qv;
            float q0 = qa[i][0] + bqv[0], q1 = qa[i][1] + bqv[1];
            float q2 = qa[i][2] + bqv[2], q3 = qa[i][3] + bqv[3];
            qv.x = (q0 > 0.f) ? 1.f + q0 : __expf(q0);
            qv.y = (q1 > 0.f) ? 1.f + q1 : __expf(q1);
            qv.z = (q2 > 0.f) ? 1.f + q2 : __expf(q2);
            qv.w = (q3 > 0.f) ? 1.f + q3 : __expf(q3);
            *(float4*)&Qg[(size_t)(n0 + r0 + i) * kHID + tx * 4] = qv;
        }
    }
    __syncthreads();
#pragma unroll
    for (int i = 0; i < 4; ++i) {
        int slot = t + 256 * i;
        int row = slot >> 4, cg = slot & 15;
        *(float4*)&sW[row * 68 + cg * 4] = *(const float4*)&Wk[(size_t)row * kHID + cg * 4];
    }
    __syncthreads();

    float ka[2][4];
#pragma unroll
    for (int i = 0; i < 2; ++i)
#pragma unroll
        for (int j = 0; j < 4; ++j) ka[i][j] = 0.f;
#pragma unroll 8
    for (int kk = 0; kk < 64; ++kk) {
        float4 b = *(float4*)&sW[kk * 68 + tx * 4];
        float a0 = sX[r0 * 68 + kk], a1 = sX[r1 * 68 + kk];
        ka[0][0] += a0 * b.x; ka[0][1] += a0 * b.y;
        ka[0][2] += a0 * b.z; ka[0][3] += a0 * b.w;
        ka[1][0] += a1 * b.x; ka[1][1] += a1 * b.y;
        ka[1][2] += a1 * b.z; ka[1][3] += a1 * b.w;
    }
    {
        float bkv[4];
#pragma unroll
        for (int j = 0; j < 4; ++j) bkv[j] = bk[tx * 4 + j];
#pragma unroll
        for (int i = 0; i < 2; ++i) {
            float4 kv;
            float k0v = ka[i][0] + bkv[0], k1v = ka[i][1] + bkv[1];
            float k2v = ka[i][2] + bkv[2], k3v = ka[i][3] + bkv[3];
            kv.x = (k0v > 0.f) ? 1.f + k0v : __expf(k0v);
            kv.y = (k1v > 0.f) ? 1.f + k1v : __expf(k1v);
            kv.z = (k2v > 0.f) ? 1.f + k2v : __expf(k2v);
            kv.w = (k3v > 0.f) ? 1.f + k3v : __expf(k3v);
            *(float4*)&Ktg[(size_t)(n0 + r0 + i) * kHID + tx * 4] = kv;
        }
    }
    __syncthreads();
#pragma unroll
    for (int i = 0; i < 3; ++i) {
        int slot = t + 256 * i;
        if (slot < 640) {
            int row = slot / 10, cg = slot % 10;
            *(float4*)&sW[row * 44 + cg * 4] = *(const float4*)&Wv[(size_t)row * 40 + cg * 4];
        }
    }
    __syncthreads();

    if (t < 160) {
        int txv = t % 10, tyv = t / 10;
        int vr0 = tyv * 2;
        float va[2][4];
#pragma unroll
        for (int i = 0; i < 2; ++i)
#pragma unroll
            for (int j = 0; j < 4; ++j) va[i][j] = 0.f;
#pragma unroll 8
        for (int kk = 0; kk < 64; ++kk) {
            float4 b = *(float4*)&sW[kk * 44 + txv * 4];
            float a0 = sX[vr0 * 68 + kk], a1 = sX[(vr0 + 1) * 68 + kk];
            va[0][0] += a0 * b.x; va[0][1] += a0 * b.y;
            va[0][2] += a0 * b.z; va[0][3] += a0 * b.w;
            va[1][0] += a1 * b.x; va[1][1] += a1 * b.y;
            va[1][2] += a1 * b.z; va[1][3] += a1 * b.w;
        }
        float bvv[4];
#pragma unroll
        for (int j = 0; j < 4; ++j) bvv[j] = bv[txv * 4 + j];
        float hw0 = hopwise[0];
#pragma unroll
        for (int i = 0; i < 2; ++i) {
            int row = vr0 + i;
            float4 vr;
            vr.x = va[i][0] + bvv[0]; vr.y = va[i][1] + bvv[1];
            vr.z = va[i][2] + bvv[2]; vr.w = va[i][3] + bvv[3];
            *(float4*)&Vg[(size_t)(n0 + row) * 40 + txv * 4] = vr;
            float4 hr;
            hr.x = vr.x * hw0; hr.y = vr.y * hw0; hr.z = vr.z * hw0; hr.w = vr.w * hw0;
            *(float4*)&hidden[(size_t)(n0 + row) * 40 + txv * 4] = hr;
        }
    }
}

// ---- hop 0, rank-1, lane-local K + direct V loads (r12-proven).
//      Writes M1 (canonical words 5l..5l+4) + Kt1 in BF16.
__global__ __launch_bounds__(256) void hop0_kernel(
    const int* __restrict__ ptr, const int* __restrict__ src, const float* __restrict__ wgt,
    const float* __restrict__ Ktin, const float* __restrict__ Vin,
    const float* __restrict__ Q,
    uint16_t* __restrict__ Mout, uint16_t* __restrict__ Ktout,
    float* __restrict__ hidden, const float* __restrict__ gammas) {
    __shared__ float Ml[4][640];
    __shared__ float Ktl[4][64];
    __shared__ float Ql[4][64];
    int w = threadIdx.x >> 6;
    int l = threadIdx.x & 63;
    int n = blockIdx.x * 4 + w;
    int beg = ptr[n], end = ptr[n + 1];

    Ql[w][l] = Q[(size_t)n * 64 + l];

    int base_v = 10 * (l >> 4);

    float m[10];
#pragma unroll
    for (int i = 0; i < 10; ++i) m[i] = 0.f;
    float kacc = 0.f;

    auto edge = [&](int su, float wv) {
        float kl = Ktin[(size_t)su * 64 + l];
        const float* vr = Vin + (size_t)su * 40 + base_v;
        float2 v0 = *(const float2*)vr;
        float2 v1 = *(const float2*)(vr + 2);
        float2 v2 = *(const float2*)(vr + 4);
        float2 v3 = *(const float2*)(vr + 6);
        float2 v4 = *(const float2*)(vr + 8);
        float kw = wv * kl;
        kacc += wv * kl;
        m[0] += kw * v0.x; m[1] += kw * v0.y;
        m[2] += kw * v1.x; m[3] += kw * v1.y;
        m[4] += kw * v2.x; m[5] += kw * v2.y;
        m[6] += kw * v3.x; m[7] += kw * v3.y;
        m[8] += kw * v4.x; m[9] += kw * v4.y;
    };

    int e = beg;
    for (; e + 4 <= end; e += 4) {
        int s0 = src[e], s1 = src[e + 1], s2 = src[e + 2], s3 = src[e + 3];
        float w0 = wgt[e], w1 = wgt[e + 1], w2 = wgt[e + 2], w3 = wgt[e + 3];
        edge(s0, w0); edge(s1, w1); edge(s2, w2); edge(s3, w3);
    }
    for (; e < end; ++e) edge(src[e], wgt[e]);

    // write M1 (canonical words 5l..5l+4) + Kt1 (bf16)
    {
        uint32_t* orow = (uint32_t*)Mout + (size_t)n * 320 + 5 * l;
        orow[0] = pack2(m[0], m[1]);
        orow[1] = pack2(m[2], m[3]);
        orow[2] = pack2(m[4], m[5]);
        orow[3] = pack2(m[6], m[7]);
        orow[4] = pack2(m[8], m[9]);
        Ktout[(size_t)n * 64 + l] = f2bf(kacc);
    }
#pragma unroll
    for (int c = 0; c < 10; c += 2)
        *(float2*)&Ml[w][10 * l + c] = make_float2(m[c], m[c + 1]);
    Ktl[w][l] = kacc;
    __syncthreads();

    int tt = threadIdx.x;
    if (tt < 160) {
        int ww = tt / 40, o = tt % 40;
        int h = o / 10, j = o % 10;
        const float* q  = &Ql[ww][h * 16];
        const float* kk = &Ktl[ww][h * 16];
        const float* mm = &Ml[ww][h * 160 + j];
        float cd = kCST, hh = 0.f;
#pragma unroll
        for (int i = 0; i < 16; ++i) { cd += q[i] * kk[i]; hh += q[i] * mm[i * 10]; }
        int nn = blockIdx.x * 4 + ww;
        hidden[(size_t)nn * 40 + o] += gammas[h] * hh / cd;
    }
}

// ---- hops 1-2, wave-per-node (r9-structure): gather M (bf16, 5 dwords/lane,
//      plane layout) & Kt (BF16 ushort/lane — halves the Kt gather stream),
//      4-edge unroll; Hh/Cd epilogue. LAST: no writeback, fused output GEMM.
template<bool LAST>
__global__ __launch_bounds__(256) void hop2_kernel(
    const int* __restrict__ ptr, const int* __restrict__ src, const float* __restrict__ wgt,
    const uint16_t* __restrict__ Min, uint16_t* __restrict__ Mout,
    const uint16_t* __restrict__ Ktin, uint16_t* __restrict__ Ktout,
    const float* __restrict__ Q, float* __restrict__ hidden,
    const float* __restrict__ gammas,
    const float* __restrict__ W_out, const float* __restrict__ b_out,
    float* __restrict__ out) {
    __shared__ float Ml[4][640];
    __shared__ float Ktl[4][64];
    __shared__ float Ql[4][64];
    __shared__ float Hl[4][40];
    int w = threadIdx.x >> 6;     // node slot
    int l = threadIdx.x & 63;     // lane
    int n = blockIdx.x * 4 + w;
    int beg = ptr[n], end = ptr[n + 1];
    const uint32_t* Mw = (const uint32_t*)Min;

    Ql[w][l] = Q[(size_t)n * 64 + l];   // hoisted: overlaps with gather

    float m0=0,m1=0,m2=0,m3=0,m4=0,m5=0,m6=0,m7=0,m8=0,m9=0;
    float kacc = 0.f;
    int e = beg;
    for (; e + 4 <= end; e += 4) {
        int s0 = src[e], s1 = src[e + 1], s2 = src[e + 2], s3 = src[e + 3];
        float w0 = wgt[e], w1 = wgt[e + 1], w2 = wgt[e + 2], w3 = wgt[e + 3];
        const uint32_t* p0 = Mw + (size_t)s0 * 320 + l;
        const uint32_t* p1 = Mw + (size_t)s1 * 320 + l;
        const uint32_t* p2 = Mw + (size_t)s2 * 320 + l;
        const uint32_t* p3 = Mw + (size_t)s3 * 320 + l;
        uint32_t a0 = p0[0], a1 = p0[64], a2 = p0[128], a3 = p0[192], a4 = p0[256];
        uint32_t b0 = p1[0], b1 = p1[64], b2 = p1[128], b3 = p1[192], b4 = p1[256];
        uint32_t c0 = p2[0], c1 = p2[64], c2 = p2[128], c3 = p2[192], c4 = p2[256];
        uint32_t d0 = p3[0], d1 = p3[64], d2 = p3[128], d3 = p3[192], d4 = p3[256];
        float ka = bf2f(Ktin[(size_t)s0 * 64 + l]), kb = bf2f(Ktin[(size_t)s1 * 64 + l]);
        float kc = bf2f(Ktin[(size_t)s2 * 64 + l]), kd = bf2f(Ktin[(size_t)s3 * 64 + l]);
        m0 += w0 * lo16(a0); m1 += w0 * hi16(a0);
        m2 += w0 * lo16(a1); m3 += w0 * hi16(a1);
        m4 += w0 * lo16(a2); m5 += w0 * hi16(a2);
        m6 += w0 * lo16(a3); m7 += w0 * hi16(a3);
        m8 += w0 * lo16(a4); m9 += w0 * hi16(a4);
        m0 += w1 * lo16(b0); m1 += w1 * hi16(b0);
        m2 += w1 * lo16(b1); m3 += w1 * hi16(b1);
        m4 += w1 * lo16(b2); m5 += w1 * hi16(b2);
        m6 += w1 * lo16(b3); m7 += w1 * hi16(b3);
        m8 += w1 * lo16(b4); m9 += w1 * hi16(b4);
        m0 += w2 * lo16(c0); m1 += w2 * hi16(c0);
        m2 += w2 * lo16(c1); m3 += w2 * hi16(c1);
        m4 += w2 * lo16(c2); m5 += w2 * hi16(c2);
        m6 += w2 * lo16(c3); m7 += w2 * hi16(c3);
        m8 += w2 * lo16(c4); m9 += w2 * hi16(c4);
        m0 += w3 * lo16(d0); m1 += w3 * hi16(d0);
        m2 += w3 * lo16(d1); m3 += w3 * hi16(d1);
        m4 += w3 * lo16(d2); m5 += w3 * hi16(d2);
        m6 += w3 * lo16(d3); m7 += w3 * hi16(d3);
        m8 += w3 * lo16(d4); m9 += w3 * hi16(d4);
        kacc += w0 * ka + w1 * kb + w2 * kc + w3 * kd;
    }
    for (; e + 2 <= end; e += 2) {
        int s0 = src[e], s1 = src[e + 1];
        float w0 = wgt[e], w1 = wgt[e + 1];
        const uint32_t* p0 = Mw + (size_t)s0 * 320 + l;
        const uint32_t* p1 = Mw + (size_t)s1 * 320 + l;
        uint32_t a0 = p0[0], a1 = p0[64], a2 = p0[128], a3 = p0[192], a4 = p0[256];
        uint32_t b0 = p1[0], b1 = p1[64], b2 = p1[128], b3 = p1[192], b4 = p1[256];
        float ka = bf2f(Ktin[(size_t)s0 * 64 + l]), kb = bf2f(Ktin[(size_t)s1 * 64 + l]);
        m0 += w0 * lo16(a0); m1 += w0 * hi16(a0);
        m2 += w0 * lo16(a1); m3 += w0 * hi16(a1);
        m4 += w0 * lo16(a2); m5 += w0 * hi16(a2);
        m6 += w0 * lo16(a3); m7 += w0 * hi16(a3);
        m8 += w0 * lo16(a4); m9 += w0 * hi16(a4);
        m0 += w1 * lo16(b0); m1 += w1 * hi16(b0);
        m2 += w1 * lo16(b1); m3 += w1 * hi16(b1);
        m4 += w1 * lo16(b2); m5 += w1 * hi16(b2);
        m6 += w1 * lo16(b3); m7 += w1 * hi16(b3);
        m8 += w1 * lo16(b4); m9 += w1 * hi16(b4);
        kacc += w0 * ka + w1 * kb;
    }
    if (e < end) {
        int s0 = src[e];
        float w0 = wgt[e];
        const uint32_t* p0 = Mw + (size_t)s0 * 320 + l;
        uint32_t a0 = p0[0], a1 = p0[64], a2 = p0[128], a3 = p0[192], a4 = p0[256];
        float ka = bf2f(Ktin[(size_t)s0 * 64 + l]);
        m0 += w0 * lo16(a0); m1 += w0 * hi16(a0);
        m2 += w0 * lo16(a1); m3 += w0 * hi16(a1);
        m4 += w0 * lo16(a2); m5 += w0 * hi16(a2);
        m6 += w0 * lo16(a3); m7 += w0 * hi16(a3);
        m8 += w0 * lo16(a4); m9 += w0 * hi16(a4);
        kacc += w0 * ka;
    }

    // stage to LDS (word (l+64c) holds values 2(l+64c), 2(l+64c)+1)
    *(float2*)&Ml[w][2 * l]         = make_float2(m0, m1);
    *(float2*)&Ml[w][2 * (l + 64)]  = make_float2(m2, m3);
    *(float2*)&Ml[w][2 * (l + 128)] = make_float2(m4, m5);
    *(float2*)&Ml[w][2 * (l + 192)] = make_float2(m6, m7);
    *(float2*)&Ml[w][2 * (l + 256)] = make_float2(m8, m9);
    Ktl[w][l] = kacc;
    if constexpr (!LAST) {
        uint32_t* orow = (uint32_t*)Mout + (size_t)n * 320 + l;
        orow[0]   = pack2(m0, m1);
        orow[64]  = pack2(m2, m3);
        orow[128] = pack2(m4, m5);
        orow[192] = pack2(m6, m7);
        orow[256] = pack2(m8, m9);
        Ktout[(size_t)n * 64 + l] = f2bf(kacc);
    }
    __syncthreads();

    int tt = threadIdx.x;
    if (tt < 160) {
        int ww = tt / 40, o = tt % 40;
        int h = o / 10, j = o % 10;
        const float* q  = &Ql[ww][h * 16];
        const float* kk = &Ktl[ww][h * 16];
        const float* mm = &Ml[ww][h * 160 + j];
        float cd = kCST, hh = 0.f;
#pragma unroll
        for (int i = 0; i < 16; ++i) { cd += q[i] * kk[i]; hh += q[i] * mm[i * 10]; }
        int nn = blockIdx.x * 4 + ww;
        float val = hidden[(size_t)nn * 40 + o] + gammas[h] * hh / cd;
        if constexpr (!LAST) hidden[(size_t)nn * 40 + o] = val;
        else Hl[ww][o] = val;
    }
    if constexpr (LAST) {
        __syncthreads();
        if (tt < 40) {
            int ww = tt / 10, c = tt % 10;
            float acc = b_out[c];
#pragma unroll
            for (int i = 0; i < 40; ++i) acc += Hl[ww][i] * W_out[i * 10 + c];
            out[(size_t)(blockIdx.x * 4 + ww) * 10 + c] = acc;
        }
    }
}

extern "C" void kernel_launch(void* const* d_in, const int* in_sizes, int n_in,
                              void* d_out, int out_size, void* d_ws, size_t ws_size,
                              hipStream_t stream) {
    const float* feat   = (const float*)d_in[0];
    const int*   ei     = (const int*)d_in[1];
    const float* W_in   = (const float*)d_in[2];
    const float* b_in   = (const float*)d_in[3];
    const float* Wq     = (const float*)d_in[4];
    const float* bq     = (const float*)d_in[5];
    const float* Wk     = (const float*)d_in[6];
    const float* bk     = (const float*)d_in[7];
    const float* Wv     = (const float*)d_in[8];
    const float* bv     = (const float*)d_in[9];
    const float* W_out  = (const float*)d_in[10];
    const float* b_out  = (const float*)d_in[11];
    const float* hopwise= (const float*)d_in[12];
    const float* temp   = (const float*)d_in[13];
    float* out = (float*)d_out;

    char* ws = (char*)d_ws;
    size_t off = 0;
    auto alloc = [&](size_t bytes) -> void* {
        void* p = ws + off;
        off += (bytes + 255) & ~(size_t)255;
        return p;
    };
    int*      deg    = (int*)alloc((size_t)kN * 4);
    int*      cursor = (int*)alloc((size_t)kN * 4);
    int*      ptr    = (int*)alloc((size_t)(kN + 1) * 4);
    int*      partial= (int*)alloc((size_t)kNB * 4);
    int*      csrc   = (int*)alloc((size_t)kET * 4);
    float*    cwgt   = (float*)alloc((size_t)kET * 4);
    float*    Q      = (float*)alloc((size_t)kN * kHID * 4);
    float*    Kt0    = (float*)alloc((size_t)kN * kHID * 4);
    uint16_t* Kt1    = (uint16_t*)alloc((size_t)kN * kHID * 2);
    uint16_t* Kt2    = (uint16_t*)alloc((size_t)kN * kHID * 2);
    float*    Vg     = (float*)alloc((size_t)kN * kH * kC * 4);
    float*    hidden = (float*)alloc((size_t)kN * kH * kC * 4);
    float*    gammas = (float*)alloc(64);
    uint16_t* M1     = (uint16_t*)alloc((size_t)kN * 640 * 2);
    uint16_t* M2     = (uint16_t*)alloc((size_t)kN * 640 * 2);
    (void)ws_size; (void)in_sizes; (void)n_in; (void)out_size;

    // deg & cursor are adjacent in ws: one memset covers both
    size_t deg_span = (size_t)((char*)cursor - (char*)deg) + (size_t)kN * 4;
    hipMemsetAsync(deg, 0, deg_span, stream);

    deg_kernel<<<(kET + 255) / 256, 256, 0, stream>>>(ei, deg);
    degsum_kernel<<<kNB, 256, 0, stream>>>(deg, partial, hopwise, temp, gammas);
    ptrw_kernel<<<kNB, 256, 0, stream>>>(deg, partial, ptr);
    scatter_kernel<<<(kET + 255) / 256, 256, 0, stream>>>(ei, deg, ptr, cursor, csrc, cwgt);
    proj_kernel<<<kN / kBN, 256, 0, stream>>>(feat, W_in, b_in, Wq, bq, Wk, bk, Wv, bv,
                                              hopwise, Q, Kt0, hidden, Vg);
    // hop 0 (rank-1 factors): Kt0(f32),Vg -> M1, Kt1(bf16)
    hop0_kernel<<<kN / 4, 256, 0, stream>>>(ptr, csrc, cwgt, Kt0, Vg, Q, M1, Kt1, hidden,
                                            gammas + 0);
    // hop 1: M1 -> M2, Kt1 -> Kt2
    hop2_kernel<false><<<kN / 4, 256, 0, stream>>>(ptr, csrc, cwgt, M1, M2, Kt1, Kt2, Q, hidden,
                                                   gammas + 4, W_out, b_out, out);
    // hop 2 (last): M2, Kt2 readout only + fused output GEMM
    hop2_kernel<true><<<kN / 4, 256, 0, stream>>>(ptr, csrc, cwgt, M2, M1, Kt2, Kt1, Q, hidden,
                                                  gammas + 8, W_out, b_out, out);
}